// Round 5
// baseline (890.211 us; speedup 1.0000x reference)
//
#include <hip/hip_runtime.h>

// ---------------------------------------------------------------------------
// SharedPPOSoftModularizedMLP on MI355X (gfx950)
// B=8192, OBS=128, TASK=64, D=1024, E=8, L=4
// bf16 MFMA (16x16x32), fp32 accumulate.
// R5: LDS=32KB exactly (seg-XOR epilogue tile) for +1 block/CU; pointer-bump
//     staging (VALU down); fused prep kernel + head->out direct (27->15
//     launches).
// ---------------------------------------------------------------------------

typedef __attribute__((ext_vector_type(8))) short short8;   // 8 x bf16 frag
typedef __attribute__((ext_vector_type(4))) float floatx4;  // MFMA acc
typedef unsigned short us;

__device__ __forceinline__ us f2bf(float f) {
  union { float f; unsigned u; } v; v.f = f;
  return (us)((v.u + 0x7FFFu + ((v.u >> 16) & 1u)) >> 16);  // RNE
}
__device__ __forceinline__ float bf2f(us h) {
  union { unsigned u; float f; } v; v.u = ((unsigned)h) << 16;
  return v.f;
}

// async global->LDS, 16B per lane; lds dest = wave-uniform base + lane*16
__device__ __forceinline__ void g2lds16(const void* g, void* l) {
  __builtin_amdgcn_global_load_lds(
      (const __attribute__((address_space(1))) void*)g,
      (__attribute__((address_space(3))) void*)l, 16, 0, 0);
}

// ---------------------------------------------------------------------------
// C[M,N] = post(act(A[M,K]@Bt[N,K]^T + bias[N])); A,Bt bf16.
// post: optional elementwise Mul[M,N] (bf16), then optional relu2.
// Cb2 != 0: Cb = value, Cb2 = relu(value) (dual bf16 output).
// atomic: split-K over blockIdx.z, atomicAdd into Cf; headout remaps cols
//   (col<8 -> out[(rowoff+row)*8+col], col==8 -> out[Btot*8+rowoff+row]).
// grid=(ceil(N/128), M/128, Z). XCD chunk swizzle when total blocks % 8 == 0.
// ---------------------------------------------------------------------------
__global__ __launch_bounds__(256)
void gemm_bt(const us* __restrict__ A, const us* __restrict__ Bt,
             const float* __restrict__ bias,
             us* __restrict__ Cb, us* __restrict__ Cb2,
             float* __restrict__ Cf, const us* __restrict__ Mul,
             int M, int N, int K, int lda, int ldb,
             long long sA, long long sB, long long sBias, long long sC,
             int relu, int relu2, int atomic, int headout, int rowoff, int Btot)
{
  // ---- XCD chunk swizzle: each XCD gets a contiguous slice of work ----
  int bx = blockIdx.x, by = blockIdx.y, bz = blockIdx.z;
  {
    const int gx = gridDim.x, gy = gridDim.y;
    const int total = gx * gy * gridDim.z;
    if ((total & 7) == 0) {
      int L = bx + gx * (by + gy * bz);
      int per = total >> 3;
      int w = (L & 7) * per + (L >> 3);   // XCD id * chunk + slot
      bx = w % gx; w /= gx;
      by = w % gy; bz = w / gy;
    }
  }

  const int e = bz;
  const us* Ab = A + (size_t)e * sA;
  const us* Bb = Bt + (size_t)e * sB;
  const float* biasb = bias ? bias + (size_t)e * sBias : (const float*)0;

  const int m0 = by * 128;
  const int n0 = bx * 128;
  const int tid = threadIdx.x;
  const int wave = tid >> 6;
  const int lane = tid & 63;
  const int wm = (wave >> 1) * 64;
  const int wn = (wave & 1) * 64;
  const int lr = lane & 15;
  const int lq = lane >> 4;

  // 32768 B exactly: staging A|B (2 x 8192 us) OR epilogue tile (128x128 us)
  __shared__ __align__(16) us smem[128 * 128];
  us* ldsA = smem;
  us* ldsB = smem + 128 * 64;

  floatx4 acc[4][4];
#pragma unroll
  for (int i = 0; i < 4; ++i)
#pragma unroll
    for (int j = 0; j < 4; ++j) acc[i][j] = (floatx4){0.f, 0.f, 0.f, 0.f};

  // precompute staging pointers; bump by 64 elements per K-iter
  const us* gA[4];
  const us* gB[4];
  int ub[4];
#pragma unroll
  for (int c = 0; c < 4; ++c) {
    int slot = c * 256 + tid;               // physical 16B chunk
    int r = slot >> 3;
    int s = (slot & 7) ^ (r & 7);           // logical slab (XOR swizzle)
    ub[c] = (c * 256 + wave * 64) * 8;      // wave-uniform LDS base (us)
    gA[c] = Ab + (size_t)(m0 + r) * lda + s * 8;
    int nrow = n0 + r; if (nrow > N - 1) nrow = N - 1;  // clamp (N<128)
    gB[c] = Bb + (size_t)nrow * ldb + s * 8;
  }

  for (int k0 = 0; k0 < K; k0 += 64) {
#pragma unroll
    for (int c = 0; c < 4; ++c) {
      g2lds16(gA[c], ldsA + ub[c]);
      g2lds16(gB[c], ldsB + ub[c]);
      gA[c] += 64; gB[c] += 64;
    }
    __syncthreads();

#pragma unroll
    for (int kk = 0; kk < 2; ++kk) {
      short8 af[4], bfr[4];
#pragma unroll
      for (int t = 0; t < 4; ++t) {
        int m = wm + t * 16 + lr;
        int s = kk * 4 + lq;
        af[t]  = *(const short8*)(ldsA + (size_t)(m * 8 + (s ^ (m & 7))) * 8);
        int n = wn + t * 16 + lr;
        bfr[t] = *(const short8*)(ldsB + (size_t)(n * 8 + (s ^ (n & 7))) * 8);
      }
#pragma unroll
      for (int mt = 0; mt < 4; ++mt)
#pragma unroll
        for (int nt = 0; nt < 4; ++nt)
          acc[mt][nt] = __builtin_amdgcn_mfma_f32_16x16x32_bf16(
              af[mt], bfr[nt], acc[mt][nt], 0, 0, 0);
    }
    __syncthreads();
  }

  // ---- epilogue.  C/D layout: col = lane&15, row = lq*4 + r ----
  const bool vecpath = (Cb && !Cf && (N % 128 == 0));
  if (vecpath) {
    // stage bf16 tile into LDS, stride 128 with seg-XOR swizzle
#pragma unroll
    for (int nt = 0; nt < 4; ++nt) {
      int coll = wn + nt * 16 + lr;
      int col = n0 + coll;
      int seg = coll >> 3, cw = coll & 7;
      float bv = biasb ? biasb[col] : 0.f;
#pragma unroll
      for (int mt = 0; mt < 4; ++mt) {
        int rowb = wm + mt * 16 + lq * 4;
#pragma unroll
        for (int r = 0; r < 4; ++r) {
          int rowl = rowb + r;
          float v = acc[mt][nt][r] + bv;
          if (relu) v = fmaxf(v, 0.f);
          if (Mul) v *= bf2f(Mul[(size_t)(m0 + rowl) * N + col]);
          if (relu2) v = fmaxf(v, 0.f);
          smem[rowl * 128 + ((seg ^ (rowl & 7)) << 3) + cw] = f2bf(v);
        }
      }
    }
    __syncthreads();
    // read back row-major 16B/lane; coalesced dwordx4 stores
#pragma unroll
    for (int c = 0; c < 8; ++c) {
      int sl = c * 256 + tid;
      int rowl = sl >> 4;
      int seg = sl & 15;
      short8 val = *(const short8*)(smem + rowl * 128 + ((seg ^ (rowl & 7)) << 3));
      size_t gidx = (size_t)e * sC + (size_t)(m0 + rowl) * N + n0 + seg * 8;
      *(short8*)(Cb + gidx) = val;
      if (Cb2) {
        short8 rl;
#pragma unroll
        for (int q = 0; q < 8; ++q) {
          us u = (us)val[q];
          rl[q] = (short)((u & 0x8000u) ? (us)0 : u);
        }
        *(short8*)(Cb2 + gidx) = rl;
      }
    }
  } else {
#pragma unroll
    for (int nt = 0; nt < 4; ++nt) {
      int col = n0 + wn + nt * 16 + lr;
      if (col >= N) continue;
      float bv = biasb ? biasb[col] : 0.f;
#pragma unroll
      for (int mt = 0; mt < 4; ++mt) {
        int row = m0 + wm + mt * 16 + lq * 4;
#pragma unroll
        for (int r = 0; r < 4; ++r) {
          float v = acc[mt][nt][r] + bv;
          if (relu) v = fmaxf(v, 0.f);
          if (Mul) v *= bf2f(Mul[(size_t)(row + r) * N + col]);
          if (relu2) v = fmaxf(v, 0.f);
          if (atomic) {
            if (headout) {
              size_t di = (col < 8) ? ((size_t)(rowoff + row + r) * 8 + col)
                                    : ((size_t)Btot * 8 + rowoff + row + r);
              atomicAdd(Cf + di, v);
            } else {
              atomicAdd(Cf + (size_t)(row + r) * N + col, v);
            }
            continue;
          }
          size_t idx = (size_t)e * sC + (size_t)(row + r) * N + col;
          if (Cf) Cf[idx] = v;
          if (Cb) Cb[idx] = f2bf(v);
          if (Cb2) Cb2[idx] = f2bf(fmaxf(v, 0.f));
        }
      }
    }
  }
}

// ---------------------------------------------------------------------------
// Fused prep: all weight transposes (fp32 [R,C] -> bf16 [C,R]), Wh build,
// pbuf zero, out bias init, x split/convert.  One launch, range ladder.
// ---------------------------------------------------------------------------
__device__ __forceinline__ void transpose_tile(
    const float* __restrict__ in, us* __restrict__ out,
    int R, int C, int bx, int by, float (*tile)[33])
{
  const int tx = threadIdx.x & 31, ty = threadIdx.x >> 5;
  const int c0 = bx * 32, r0 = by * 32;
#pragma unroll
  for (int i = 0; i < 4; ++i) {
    int r = r0 + ty + i * 8, c = c0 + tx;
    tile[ty + i * 8][tx] = (r < R && c < C) ? in[(size_t)r * C + c] : 0.f;
  }
  __syncthreads();
#pragma unroll
  for (int i = 0; i < 4; ++i) {
    int c = c0 + ty + i * 8, r = r0 + tx;
    if (c < C && r < R) out[(size_t)c * R + r] = f2bf(tile[tx][ty + i * 8]);
  }
}

__global__ __launch_bounds__(256)
void prep_kernel(const float* __restrict__ x,
                 const float* __restrict__ sW1, const float* __restrict__ sW2,
                 const float* __restrict__ sW3, const float* __restrict__ tW,
                 const float* __restrict__ rdW, const float* __restrict__ ruW,
                 const float* __restrict__ eW,
                 const float* __restrict__ aW, const float* __restrict__ cW,
                 const float* __restrict__ ab, const float* __restrict__ cb,
                 us* __restrict__ obs, us* __restrict__ task,
                 us* __restrict__ s1t, us* __restrict__ s2t,
                 us* __restrict__ s3t, us* __restrict__ tWt,
                 us* __restrict__ rdt, us* __restrict__ rut,
                 us* __restrict__ eWt, us* __restrict__ Wh,
                 float* __restrict__ pbuf, float* __restrict__ out)
{
  __shared__ float tile[32][33];
  int b = blockIdx.x;
  const int tid = threadIdx.x;

  if (b < 64)  { transpose_tile(sW1, s1t, 128, 512, b % 16, b / 16, tile); return; }
  b -= 64;
  if (b < 256) { transpose_tile(sW2, s2t, 512, 512, b % 16, b / 16, tile); return; }
  b -= 256;
  if (b < 512) { transpose_tile(sW3, s3t, 512, 1024, b % 32, b / 32, tile); return; }
  b -= 512;
  if (b < 64)  { transpose_tile(tW, tWt, 64, 1024, b % 32, b / 32, tile); return; }
  b -= 64;
  if (b < 128) { int l = b >> 6, r = b & 63;
                 transpose_tile(rdW + (size_t)l * 65536, rdt + (size_t)l * 65536,
                                1024, 64, r % 2, r / 2, tile); return; }
  b -= 128;
  if (b < 64)  { transpose_tile(ruW, rut, 64, 1024, b % 32, b / 32, tile); return; }
  b -= 64;
  if (b < 16384) { int l = b >> 10, r = b & 1023;
                 transpose_tile(eW + (size_t)l * 1048576, eWt + (size_t)l * 1048576,
                                1024, 1024, r % 32, r / 32, tile); return; }
  b -= 16384;
  if (b < 288) {  // Wh[o][e*1024+d] = aW[e][d][o] (o<8) | cW[e][d]
    int i = b * 256 + tid;
    int o = i / 8192, k = i - o * 8192;
    float v = (o < 8) ? aW[(size_t)k * 8 + o] : cW[k];
    Wh[i] = f2bf(v);
    return;
  }
  b -= 288;
  if (b < 4096) { pbuf[(size_t)b * 256 + tid] = 0.f; return; }
  b -= 4096;
  if (b < 288) {  // out bias init: mu gets sum_e ab, values gets sum_e cb
    int i = b * 256 + tid;
    int bb = i / 9, o = i - bb * 9;
    float s = 0.f;
    if (o < 8) { for (int e = 0; e < 8; ++e) s += ab[e * 8 + o]; }
    else       { for (int e = 0; e < 8; ++e) s += cb[e]; }
    if (o < 8) out[(size_t)bb * 8 + o] = s;
    else       out[(size_t)8192 * 8 + bb] = s;
    return;
  }
  b -= 288;
  {  // split x(B,192) -> obs (B,128), task (B,64)
    int i = b * 256 + tid;
    int bb = i / 192, c = i - bb * 192;
    us v = f2bf(x[i]);
    if (c < 128) obs[(size_t)bb * 128 + c] = v;
    else         task[(size_t)bb * 64 + (c - 128)] = v;
  }
}

// pbuf[i] += rdb[i&63]; pbf[i] = bf16(pbuf[i])
__global__ __launch_bounds__(256)
void mk_pbf(float* __restrict__ pbuf, const float* __restrict__ rdb,
            us* __restrict__ pbf, int n)
{
  int i = blockIdx.x * 256 + threadIdx.x;
  if (i >= n) return;
  float v = pbuf[i] + rdb[i & 63];
  pbuf[i] = v;
  if (pbf) pbf[i] = f2bf(v);
}

// softmax over groups of 8; groups i >= biasFrom get +bias2[(i&7)*8+j] first
__global__ __launch_bounds__(256)
void softmax8_kernel(const float* __restrict__ p, float* __restrict__ probs,
                     const float* __restrict__ bias2, int biasFrom, int total)
{
  int i = blockIdx.x * 256 + threadIdx.x;
  if (i >= total) return;
  const float4 lo = *(const float4*)(p + (size_t)i * 8);
  const float4 hi = *(const float4*)(p + (size_t)i * 8 + 4);
  float v[8] = { lo.x, lo.y, lo.z, lo.w, hi.x, hi.y, hi.z, hi.w };
  if (i >= biasFrom) {
    const float* bb = bias2 + (i & 7) * 8;
#pragma unroll
    for (int j = 0; j < 8; ++j) v[j] += bb[j];
  }
  float m = v[0];
#pragma unroll
  for (int j = 1; j < 8; ++j) m = fmaxf(m, v[j]);
  float s = 0.f;
#pragma unroll
  for (int j = 0; j < 8; ++j) { v[j] = __expf(v[j] - m); s += v[j]; }
  float inv = 1.f / s;
  float4 olo = { v[0]*inv, v[1]*inv, v[2]*inv, v[3]*inv };
  float4 ohi = { v[4]*inv, v[5]*inv, v[6]*inv, v[7]*inv };
  *(float4*)(probs + (size_t)i * 8)     = olo;
  *(float4*)(probs + (size_t)i * 8 + 4) = ohi;
}

// out[i*sOutE + bl*sOutB + d] = sum_j P[bg,i,j]*he[j,bl,d]; block per local b
__global__ __launch_bounds__(256)
void mix_kernel(const us* __restrict__ he, const float* __restrict__ probs_l,
                us* __restrict__ xx, int b0, int chunkB,
                long long sOutE, long long sOutB)
{
  const int bl = blockIdx.x;
  const int bg = b0 + bl;
  __shared__ float P[64];
  if (threadIdx.x < 64) P[threadIdx.x] = probs_l[(size_t)bg * 64 + threadIdx.x];
  __syncthreads();
  const int t = threadIdx.x;
  const size_t es = (size_t)chunkB * 1024;
  const size_t rbase = (size_t)bl * 1024 + (size_t)t * 4;
  const size_t wbase = (size_t)bl * sOutB + (size_t)t * 4;
  float hv[8][4];
#pragma unroll
  for (int j = 0; j < 8; ++j) {
    ushort4 h4 = *(const ushort4*)(he + (size_t)j * es + rbase);
    hv[j][0] = bf2f(h4.x); hv[j][1] = bf2f(h4.y);
    hv[j][2] = bf2f(h4.z); hv[j][3] = bf2f(h4.w);
  }
#pragma unroll
  for (int i = 0; i < 8; ++i) {
    float o0 = 0.f, o1 = 0.f, o2 = 0.f, o3 = 0.f;
#pragma unroll
    for (int j = 0; j < 8; ++j) {
      float pij = P[i * 8 + j];
      o0 += pij * hv[j][0]; o1 += pij * hv[j][1];
      o2 += pij * hv[j][2]; o3 += pij * hv[j][3];
    }
    ushort4 ov = { f2bf(o0), f2bf(o1), f2bf(o2), f2bf(o3) };
    *(ushort4*)(xx + (size_t)i * sOutE + wbase) = ov;
  }
}

// ---------------------------------------------------------------------------
extern "C" void kernel_launch(void* const* d_in, const int* in_sizes, int n_in,
                              void* d_out, int out_size, void* d_ws, size_t ws_size,
                              hipStream_t stream)
{
  const float* x   = (const float*)d_in[0];
  const float* sW1 = (const float*)d_in[1];
  const float* sb1 = (const float*)d_in[2];
  const float* sW2 = (const float*)d_in[3];
  const float* sb2 = (const float*)d_in[4];
  const float* sW3 = (const float*)d_in[5];
  const float* sb3 = (const float*)d_in[6];
  const float* tW  = (const float*)d_in[7];
  const float* tb  = (const float*)d_in[8];
  const float* rdW = (const float*)d_in[9];
  const float* rdb = (const float*)d_in[10];
  const float* ruW = (const float*)d_in[11];
  const float* rub = (const float*)d_in[12];
  const float* eW  = (const float*)d_in[13];
  const float* eb  = (const float*)d_in[14];
  const float* aW  = (const float*)d_in[15];
  const float* ab  = (const float*)d_in[16];
  const float* cW  = (const float*)d_in[17];
  const float* cb  = (const float*)d_in[18];
  float* out = (float*)d_out;

  const int B = 8192;
  const size_t BD = (size_t)B * 1024;
  char* ws = (char*)d_ws;

  // ---- arena: persistent region -------------------------------------------
  size_t o = 0;
  auto take = [&](size_t bytes) { size_t r = o; o = (o + bytes + 255) & ~(size_t)255; return r; };
  const size_t off_s1t  = take((size_t)512 * 128 * 2);
  const size_t off_s2t  = take((size_t)512 * 512 * 2);
  const size_t off_s3t  = take((size_t)1024 * 512 * 2);
  const size_t off_tWt  = take((size_t)1024 * 64 * 2);
  const size_t off_rdt  = take((size_t)2 * 64 * 1024 * 2);
  const size_t off_rut  = take((size_t)1024 * 64 * 2);
  const size_t off_eWt  = take((size_t)16 * 1024 * 1024 * 2);
  const size_t off_fobs = take(BD * 2);
  const size_t off_probs= take((size_t)2 * B * 64 * 4);
  const size_t off_Wh   = take((size_t)9 * 8192 * 2);
  const size_t P0 = o;
  // ---- scratch overlays (routing phase) -----------------------------------
  const size_t off_rin  = P0;                 // also h1
  const size_t off_rbuf = off_rin + BD * 2;   // also h2, u
  const size_t off_pbuf = off_rbuf + BD * 2;
  const size_t off_pbf  = off_pbuf + (size_t)2 * B * 64 * 4;
  const size_t off_obs  = off_pbf + (size_t)B * 64 * 2;
  const size_t off_task = off_obs + (size_t)B * 128 * 2;
  const size_t routing_end = off_task + (size_t)B * 64 * 2;

  // ---- expert-stage chunk selection (he/xx overlay scratch at P0) ---------
  int chunk = 0;
  const int cands[4] = {8192, 4096, 2048, 1024};
  for (int i = 0; i < 4; ++i) {
    size_t need = P0 + (size_t)cands[i] * 32768;  // he + xx
    if (need <= ws_size) { chunk = cands[i]; break; }
  }
  if (!chunk || routing_end > ws_size) return;

  us* s1t  = (us*)(ws + off_s1t);
  us* s2t  = (us*)(ws + off_s2t);
  us* s3t  = (us*)(ws + off_s3t);
  us* tWt  = (us*)(ws + off_tWt);
  us* rdt  = (us*)(ws + off_rdt);
  us* rut  = (us*)(ws + off_rut);
  us* eWt  = (us*)(ws + off_eWt);
  us* fobs = (us*)(ws + off_fobs);
  float* probs = (float*)(ws + off_probs);
  us* Wh   = (us*)(ws + off_Wh);
  us* rin  = (us*)(ws + off_rin);
  us* rbuf = (us*)(ws + off_rbuf);
  float* pbuf = (float*)(ws + off_pbuf);
  us* pbf  = (us*)(ws + off_pbf);
  us* obs_bf  = (us*)(ws + off_obs);
  us* task_bf = (us*)(ws + off_task);
  us* h1 = rin;
  us* h2 = rbuf;
  us* he = (us*)(ws + P0);
  us* xx = (us*)(ws + P0 + (size_t)chunk * 16384);  // also b-major for head

  // ---- fused prep: transposes + Wh + pbuf zero + out bias + x split -------
  // blocks: 64+256+512+64+128+64+16384+288+4096+288+6144 = 28288
  prep_kernel<<<dim3(28288), 256, 0, stream>>>(x, sW1, sW2, sW3, tW, rdW, ruW,
      eW, aW, cW, ab, cb, obs_bf, task_bf, s1t, s2t, s3t, tWt, rdt, rut,
      eWt, Wh, pbuf, out);

  // ---- shared MLP ---------------------------------------------------------
  gemm_bt<<<dim3(4, 64, 1), 256, 0, stream>>>(obs_bf, s1t, sb1, h1, (us*)0,
      (float*)0, (const us*)0, B, 512, 128, 128, 128, 0, 0, 0, 0, 1, 0, 0, 0, 0, 0);
  gemm_bt<<<dim3(4, 64, 1), 256, 0, stream>>>(h1, s2t, sb2, h2, (us*)0,
      (float*)0, (const us*)0, B, 512, 512, 512, 512, 0, 0, 0, 0, 1, 0, 0, 0, 0, 0);
  gemm_bt<<<dim3(8, 64, 1), 256, 0, stream>>>(h2, s3t, sb3, fobs, (us*)0,
      (float*)0, (const us*)0, B, 1024, 512, 512, 512, 0, 0, 0, 0, 0, 0, 0, 0, 0, 0);
  // z-GEMM fused: rin = relu(task@tW+tb)*fobs ; rbuf = relu(rin)
  gemm_bt<<<dim3(8, 64, 1), 256, 0, stream>>>(task_bf, tWt, tb, rin, rbuf,
      (float*)0, fobs, B, 1024, 64, 64, 64, 0, 0, 0, 0, 1, 0, 0, 0, 0, 0);

  // ---- routing (layers 0,1; layer 2 is dead code) -------------------------
  gemm_bt<<<dim3(1, 64, 4), 256, 0, stream>>>(rbuf, rdt, (const float*)0,
      (us*)0, (us*)0, pbuf, (const us*)0,
      B, 64, 256, 1024, 1024, 256, 256, 0, 0, 0, 0, 1, 0, 0, 0);   // p0 split-K
  mk_pbf<<<dim3((B * 64 + 255) / 256), 256, 0, stream>>>(pbuf, rdb, pbf, B * 64);
  // u-GEMM fused: rbuf = relu((pbf@ruW+rub) * rin)
  gemm_bt<<<dim3(8, 64, 1), 256, 0, stream>>>(pbf, rut, rub, rbuf, (us*)0,
      (float*)0, rin, B, 1024, 64, 64, 64, 0, 0, 0, 0, 0, 1, 0, 0, 0, 0);
  gemm_bt<<<dim3(1, 64, 4), 256, 0, stream>>>(rbuf, rdt + 65536, (const float*)0,
      (us*)0, (us*)0, pbuf + (size_t)B * 64, (const us*)0,
      B, 64, 256, 1024, 1024, 256, 256, 0, 0, 0, 0, 1, 0, 0, 0);   // p1 split-K
  // softmax; p1 half gets its rdb bias applied inline
  softmax8_kernel<<<dim3((2 * B * 8 + 255) / 256), 256, 0, stream>>>(
      pbuf, probs, rdb + 64, B * 8, 2 * B * 8);

  // ---- expert stage, chunked over batch -----------------------------------
  const long long sHE = (long long)chunk * 1024;
  for (int b0 = 0; b0 < B; b0 += chunk) {
    gemm_bt<<<dim3(8, chunk / 128, 8), 256, 0, stream>>>(
        fobs + (size_t)b0 * 1024, eWt, eb, he, (us*)0, (float*)0, (const us*)0,
        chunk, 1024, 1024, 1024, 1024, 0, 1048576, 1024, sHE, 1, 0, 0, 0, 0, 0);
    mix_kernel<<<dim3(chunk), 256, 0, stream>>>(he, probs, xx, b0, chunk, sHE, 1024);
    gemm_bt<<<dim3(8, chunk / 128, 8), 256, 0, stream>>>(
        xx, eWt + (size_t)8 * 1048576, eb + 8192, he, (us*)0, (float*)0, (const us*)0,
        chunk, 1024, 1024, 1024, 1024, sHE, 1048576, 1024, sHE, 1, 0, 0, 0, 0, 0);
    // xx reused in b-major layout [bl][e*1024+d] for the head GEMM
    mix_kernel<<<dim3(chunk), 256, 0, stream>>>(he, probs + (size_t)B * 64, xx,
        b0, chunk, 1024, 8192);
    // heads: M=chunk, N=9, K=8192, split-K=4, atomic direct into out
    gemm_bt<<<dim3(1, chunk / 128, 4), 256, 0, stream>>>(
        xx, Wh, (const float*)0, (us*)0, (us*)0, out, (const us*)0,
        chunk, 9, 2048, 8192, 8192, 2048, 2048, 0, 0, 0, 0, 1, 1, b0, B);
  }
}

// Round 6
// 890.178 us; speedup vs baseline: 1.0000x; 1.0000x over previous
//
#include <hip/hip_runtime.h>

// ---------------------------------------------------------------------------
// SharedPPOSoftModularizedMLP on MI355X (gfx950)
// B=8192, OBS=128, TASK=64, D=1024, E=8, L=4
// bf16 MFMA (16x16x32), fp32 accumulate.
// R6: revert R5's pointer-bump staging (VGPR 96->80 was the regression:
//     occupancy 31->22). Keep 32KB seg-XOR epilogue + R5 tail fusions.
// ---------------------------------------------------------------------------

typedef __attribute__((ext_vector_type(8))) short short8;   // 8 x bf16 frag
typedef __attribute__((ext_vector_type(4))) float floatx4;  // MFMA acc
typedef unsigned short us;

__device__ __forceinline__ us f2bf(float f) {
  union { float f; unsigned u; } v; v.f = f;
  return (us)((v.u + 0x7FFFu + ((v.u >> 16) & 1u)) >> 16);  // RNE
}
__device__ __forceinline__ float bf2f(us h) {
  union { unsigned u; float f; } v; v.u = ((unsigned)h) << 16;
  return v.f;
}

// async global->LDS, 16B per lane; lds dest = wave-uniform base + lane*16
__device__ __forceinline__ void g2lds16(const void* g, void* l) {
  __builtin_amdgcn_global_load_lds(
      (const __attribute__((address_space(1))) void*)g,
      (__attribute__((address_space(3))) void*)l, 16, 0, 0);
}

// ---------------------------------------------------------------------------
// C[M,N] = post(act(A[M,K]@Bt[N,K]^T + bias[N])); A,Bt bf16.
// post: optional elementwise Mul[M,N] (bf16), then optional relu2.
// Cb2 != 0: Cb = value, Cb2 = relu(value) (dual bf16 output).
// atomic: split-K over blockIdx.z, atomicAdd into Cf; headout remaps cols
//   (col<8 -> out[(rowoff+row)*8+col], col==8 -> out[Btot*8+rowoff+row]).
// grid=(ceil(N/128), M/128, Z). XCD chunk swizzle when total blocks % 8 == 0.
// ---------------------------------------------------------------------------
__global__ __launch_bounds__(256)
void gemm_bt(const us* __restrict__ A, const us* __restrict__ Bt,
             const float* __restrict__ bias,
             us* __restrict__ Cb, us* __restrict__ Cb2,
             float* __restrict__ Cf, const us* __restrict__ Mul,
             int M, int N, int K, int lda, int ldb,
             long long sA, long long sB, long long sBias, long long sC,
             int relu, int relu2, int atomic, int headout, int rowoff, int Btot)
{
  // ---- XCD chunk swizzle: each XCD gets a contiguous slice of work ----
  int bx = blockIdx.x, by = blockIdx.y, bz = blockIdx.z;
  {
    const int gx = gridDim.x, gy = gridDim.y;
    const int total = gx * gy * gridDim.z;
    if ((total & 7) == 0) {
      int L = bx + gx * (by + gy * bz);
      int per = total >> 3;
      int w = (L & 7) * per + (L >> 3);   // XCD id * chunk + slot
      bx = w % gx; w /= gx;
      by = w % gy; bz = w / gy;
    }
  }

  const int e = bz;
  const us* Ab = A + (size_t)e * sA;
  const us* Bb = Bt + (size_t)e * sB;
  const float* biasb = bias ? bias + (size_t)e * sBias : (const float*)0;

  const int m0 = by * 128;
  const int n0 = bx * 128;
  const int tid = threadIdx.x;
  const int wave = tid >> 6;
  const int lane = tid & 63;
  const int wm = (wave >> 1) * 64;
  const int wn = (wave & 1) * 64;
  const int lr = lane & 15;
  const int lq = lane >> 4;

  // 32768 B exactly: staging A|B (2 x 8192 us) OR epilogue tile (128x128 us)
  __shared__ __align__(16) us smem[128 * 128];
  us* ldsA = smem;
  us* ldsB = smem + 128 * 64;

  floatx4 acc[4][4];
#pragma unroll
  for (int i = 0; i < 4; ++i)
#pragma unroll
    for (int j = 0; j < 4; ++j) acc[i][j] = (floatx4){0.f, 0.f, 0.f, 0.f};

  for (int k0 = 0; k0 < K; k0 += 64) {
#pragma unroll
    for (int c = 0; c < 4; ++c) {
      int slot = c * 256 + tid;               // physical 16B chunk
      int r = slot >> 3;
      int s = (slot & 7) ^ (r & 7);           // logical slab (XOR swizzle)
      int ubase = (c * 256 + wave * 64) * 8;  // wave-uniform LDS base (us)
      const us* ga = Ab + (size_t)(m0 + r) * lda + k0 + s * 8;
      g2lds16(ga, ldsA + ubase);
      int nrow = n0 + r; if (nrow > N - 1) nrow = N - 1;  // clamp (N<128)
      const us* gb = Bb + (size_t)nrow * ldb + k0 + s * 8;
      g2lds16(gb, ldsB + ubase);
    }
    __syncthreads();

#pragma unroll
    for (int kk = 0; kk < 2; ++kk) {
      short8 af[4], bfr[4];
#pragma unroll
      for (int t = 0; t < 4; ++t) {
        int m = wm + t * 16 + lr;
        int s = kk * 4 + lq;
        af[t]  = *(const short8*)(ldsA + (size_t)(m * 8 + (s ^ (m & 7))) * 8);
        int n = wn + t * 16 + lr;
        bfr[t] = *(const short8*)(ldsB + (size_t)(n * 8 + (s ^ (n & 7))) * 8);
      }
#pragma unroll
      for (int mt = 0; mt < 4; ++mt)
#pragma unroll
        for (int nt = 0; nt < 4; ++nt)
          acc[mt][nt] = __builtin_amdgcn_mfma_f32_16x16x32_bf16(
              af[mt], bfr[nt], acc[mt][nt], 0, 0, 0);
    }
    __syncthreads();
  }

  // ---- epilogue.  C/D layout: col = lane&15, row = lq*4 + r ----
  const bool vecpath = (Cb && !Cf && (N % 128 == 0));
  if (vecpath) {
    // stage bf16 tile into LDS, stride 128 with seg-XOR swizzle
#pragma unroll
    for (int nt = 0; nt < 4; ++nt) {
      int coll = wn + nt * 16 + lr;
      int col = n0 + coll;
      int seg = coll >> 3, cw = coll & 7;
      float bv = biasb ? biasb[col] : 0.f;
#pragma unroll
      for (int mt = 0; mt < 4; ++mt) {
        int rowb = wm + mt * 16 + lq * 4;
#pragma unroll
        for (int r = 0; r < 4; ++r) {
          int rowl = rowb + r;
          float v = acc[mt][nt][r] + bv;
          if (relu) v = fmaxf(v, 0.f);
          if (Mul) v *= bf2f(Mul[(size_t)(m0 + rowl) * N + col]);
          if (relu2) v = fmaxf(v, 0.f);
          smem[rowl * 128 + ((seg ^ (rowl & 7)) << 3) + cw] = f2bf(v);
        }
      }
    }
    __syncthreads();
    // read back row-major 16B/lane; coalesced dwordx4 stores
#pragma unroll
    for (int c = 0; c < 8; ++c) {
      int sl = c * 256 + tid;
      int rowl = sl >> 4;
      int seg = sl & 15;
      short8 val = *(const short8*)(smem + rowl * 128 + ((seg ^ (rowl & 7)) << 3));
      size_t gidx = (size_t)e * sC + (size_t)(m0 + rowl) * N + n0 + seg * 8;
      *(short8*)(Cb + gidx) = val;
      if (Cb2) {
        short8 rl;
#pragma unroll
        for (int q = 0; q < 8; ++q) {
          us u = (us)val[q];
          rl[q] = (short)((u & 0x8000u) ? (us)0 : u);
        }
        *(short8*)(Cb2 + gidx) = rl;
      }
    }
  } else {
#pragma unroll
    for (int nt = 0; nt < 4; ++nt) {
      int col = n0 + wn + nt * 16 + lr;
      if (col >= N) continue;
      float bv = biasb ? biasb[col] : 0.f;
#pragma unroll
      for (int mt = 0; mt < 4; ++mt) {
        int row = m0 + wm + mt * 16 + lq * 4;
#pragma unroll
        for (int r = 0; r < 4; ++r) {
          float v = acc[mt][nt][r] + bv;
          if (relu) v = fmaxf(v, 0.f);
          if (Mul) v *= bf2f(Mul[(size_t)(row + r) * N + col]);
          if (relu2) v = fmaxf(v, 0.f);
          if (atomic) {
            if (headout) {
              size_t di = (col < 8) ? ((size_t)(rowoff + row + r) * 8 + col)
                                    : ((size_t)Btot * 8 + rowoff + row + r);
              atomicAdd(Cf + di, v);
            } else {
              atomicAdd(Cf + (size_t)(row + r) * N + col, v);
            }
            continue;
          }
          size_t idx = (size_t)e * sC + (size_t)(row + r) * N + col;
          if (Cf) Cf[idx] = v;
          if (Cb) Cb[idx] = f2bf(v);
          if (Cb2) Cb2[idx] = f2bf(fmaxf(v, 0.f));
        }
      }
    }
  }
}

// ---------------------------------------------------------------------------
// Fused prep: all weight transposes (fp32 [R,C] -> bf16 [C,R]), Wh build,
// pbuf zero, out bias init, x split/convert.  One launch, range ladder.
// ---------------------------------------------------------------------------
__device__ __forceinline__ void transpose_tile(
    const float* __restrict__ in, us* __restrict__ out,
    int R, int C, int bx, int by, float (*tile)[33])
{
  const int tx = threadIdx.x & 31, ty = threadIdx.x >> 5;
  const int c0 = bx * 32, r0 = by * 32;
#pragma unroll
  for (int i = 0; i < 4; ++i) {
    int r = r0 + ty + i * 8, c = c0 + tx;
    tile[ty + i * 8][tx] = (r < R && c < C) ? in[(size_t)r * C + c] : 0.f;
  }
  __syncthreads();
#pragma unroll
  for (int i = 0; i < 4; ++i) {
    int c = c0 + ty + i * 8, r = r0 + tx;
    if (c < C && r < R) out[(size_t)c * R + r] = f2bf(tile[tx][ty + i * 8]);
  }
}

__global__ __launch_bounds__(256)
void prep_kernel(const float* __restrict__ x,
                 const float* __restrict__ sW1, const float* __restrict__ sW2,
                 const float* __restrict__ sW3, const float* __restrict__ tW,
                 const float* __restrict__ rdW, const float* __restrict__ ruW,
                 const float* __restrict__ eW,
                 const float* __restrict__ aW, const float* __restrict__ cW,
                 const float* __restrict__ ab, const float* __restrict__ cb,
                 us* __restrict__ obs, us* __restrict__ task,
                 us* __restrict__ s1t, us* __restrict__ s2t,
                 us* __restrict__ s3t, us* __restrict__ tWt,
                 us* __restrict__ rdt, us* __restrict__ rut,
                 us* __restrict__ eWt, us* __restrict__ Wh,
                 float* __restrict__ pbuf, float* __restrict__ out)
{
  __shared__ float tile[32][33];
  int b = blockIdx.x;
  const int tid = threadIdx.x;

  if (b < 64)  { transpose_tile(sW1, s1t, 128, 512, b % 16, b / 16, tile); return; }
  b -= 64;
  if (b < 256) { transpose_tile(sW2, s2t, 512, 512, b % 16, b / 16, tile); return; }
  b -= 256;
  if (b < 512) { transpose_tile(sW3, s3t, 512, 1024, b % 32, b / 32, tile); return; }
  b -= 512;
  if (b < 64)  { transpose_tile(tW, tWt, 64, 1024, b % 32, b / 32, tile); return; }
  b -= 64;
  if (b < 128) { int l = b >> 6, r = b & 63;
                 transpose_tile(rdW + (size_t)l * 65536, rdt + (size_t)l * 65536,
                                1024, 64, r % 2, r / 2, tile); return; }
  b -= 128;
  if (b < 64)  { transpose_tile(ruW, rut, 64, 1024, b % 32, b / 32, tile); return; }
  b -= 64;
  if (b < 16384) { int l = b >> 10, r = b & 1023;
                 transpose_tile(eW + (size_t)l * 1048576, eWt + (size_t)l * 1048576,
                                1024, 1024, r % 32, r / 32, tile); return; }
  b -= 16384;
  if (b < 288) {  // Wh[o][e*1024+d] = aW[e][d][o] (o<8) | cW[e][d]
    int i = b * 256 + tid;
    int o = i / 8192, k = i - o * 8192;
    float v = (o < 8) ? aW[(size_t)k * 8 + o] : cW[k];
    Wh[i] = f2bf(v);
    return;
  }
  b -= 288;
  if (b < 4096) { pbuf[(size_t)b * 256 + tid] = 0.f; return; }
  b -= 4096;
  if (b < 288) {  // out bias init: mu gets sum_e ab, values gets sum_e cb
    int i = b * 256 + tid;
    int bb = i / 9, o = i - bb * 9;
    float s = 0.f;
    if (o < 8) { for (int e = 0; e < 8; ++e) s += ab[e * 8 + o]; }
    else       { for (int e = 0; e < 8; ++e) s += cb[e]; }
    if (o < 8) out[(size_t)bb * 8 + o] = s;
    else       out[(size_t)8192 * 8 + bb] = s;
    return;
  }
  b -= 288;
  {  // split x(B,192) -> obs (B,128), task (B,64)
    int i = b * 256 + tid;
    int bb = i / 192, c = i - bb * 192;
    us v = f2bf(x[i]);
    if (c < 128) obs[(size_t)bb * 128 + c] = v;
    else         task[(size_t)bb * 64 + (c - 128)] = v;
  }
}

// pbuf[i] += rdb[i&63]; pbf[i] = bf16(pbuf[i])
__global__ __launch_bounds__(256)
void mk_pbf(float* __restrict__ pbuf, const float* __restrict__ rdb,
            us* __restrict__ pbf, int n)
{
  int i = blockIdx.x * 256 + threadIdx.x;
  if (i >= n) return;
  float v = pbuf[i] + rdb[i & 63];
  pbuf[i] = v;
  if (pbf) pbf[i] = f2bf(v);
}

// softmax over groups of 8; groups i >= biasFrom get +bias2[(i&7)*8+j] first
__global__ __launch_bounds__(256)
void softmax8_kernel(const float* __restrict__ p, float* __restrict__ probs,
                     const float* __restrict__ bias2, int biasFrom, int total)
{
  int i = blockIdx.x * 256 + threadIdx.x;
  if (i >= total) return;
  const float4 lo = *(const float4*)(p + (size_t)i * 8);
  const float4 hi = *(const float4*)(p + (size_t)i * 8 + 4);
  float v[8] = { lo.x, lo.y, lo.z, lo.w, hi.x, hi.y, hi.z, hi.w };
  if (i >= biasFrom) {
    const float* bb = bias2 + (i & 7) * 8;
#pragma unroll
    for (int j = 0; j < 8; ++j) v[j] += bb[j];
  }
  float m = v[0];
#pragma unroll
  for (int j = 1; j < 8; ++j) m = fmaxf(m, v[j]);
  float s = 0.f;
#pragma unroll
  for (int j = 0; j < 8; ++j) { v[j] = __expf(v[j] - m); s += v[j]; }
  float inv = 1.f / s;
  float4 olo = { v[0]*inv, v[1]*inv, v[2]*inv, v[3]*inv };
  float4 ohi = { v[4]*inv, v[5]*inv, v[6]*inv, v[7]*inv };
  *(float4*)(probs + (size_t)i * 8)     = olo;
  *(float4*)(probs + (size_t)i * 8 + 4) = ohi;
}

// out[i*sOutE + bl*sOutB + d] = sum_j P[bg,i,j]*he[j,bl,d]; block per local b
__global__ __launch_bounds__(256)
void mix_kernel(const us* __restrict__ he, const float* __restrict__ probs_l,
                us* __restrict__ xx, int b0, int chunkB,
                long long sOutE, long long sOutB)
{
  const int bl = blockIdx.x;
  const int bg = b0 + bl;
  __shared__ float P[64];
  if (threadIdx.x < 64) P[threadIdx.x] = probs_l[(size_t)bg * 64 + threadIdx.x];
  __syncthreads();
  const int t = threadIdx.x;
  const size_t es = (size_t)chunkB * 1024;
  const size_t rbase = (size_t)bl * 1024 + (size_t)t * 4;
  const size_t wbase = (size_t)bl * sOutB + (size_t)t * 4;
  float hv[8][4];
#pragma unroll
  for (int j = 0; j < 8; ++j) {
    ushort4 h4 = *(const ushort4*)(he + (size_t)j * es + rbase);
    hv[j][0] = bf2f(h4.x); hv[j][1] = bf2f(h4.y);
    hv[j][2] = bf2f(h4.z); hv[j][3] = bf2f(h4.w);
  }
#pragma unroll
  for (int i = 0; i < 8; ++i) {
    float o0 = 0.f, o1 = 0.f, o2 = 0.f, o3 = 0.f;
#pragma unroll
    for (int j = 0; j < 8; ++j) {
      float pij = P[i * 8 + j];
      o0 += pij * hv[j][0]; o1 += pij * hv[j][1];
      o2 += pij * hv[j][2]; o3 += pij * hv[j][3];
    }
    ushort4 ov = { f2bf(o0), f2bf(o1), f2bf(o2), f2bf(o3) };
    *(ushort4*)(xx + (size_t)i * sOutE + wbase) = ov;
  }
}

// ---------------------------------------------------------------------------
extern "C" void kernel_launch(void* const* d_in, const int* in_sizes, int n_in,
                              void* d_out, int out_size, void* d_ws, size_t ws_size,
                              hipStream_t stream)
{
  const float* x   = (const float*)d_in[0];
  const float* sW1 = (const float*)d_in[1];
  const float* sb1 = (const float*)d_in[2];
  const float* sW2 = (const float*)d_in[3];
  const float* sb2 = (const float*)d_in[4];
  const float* sW3 = (const float*)d_in[5];
  const float* sb3 = (const float*)d_in[6];
  const float* tW  = (const float*)d_in[7];
  const float* tb  = (const float*)d_in[8];
  const float* rdW = (const float*)d_in[9];
  const float* rdb = (const float*)d_in[10];
  const float* ruW = (const float*)d_in[11];
  const float* rub = (const float*)d_in[12];
  const float* eW  = (const float*)d_in[13];
  const float* eb  = (const float*)d_in[14];
  const float* aW  = (const float*)d_in[15];
  const float* ab  = (const float*)d_in[16];
  const float* cW  = (const float*)d_in[17];
  const float* cb  = (const float*)d_in[18];
  float* out = (float*)d_out;

  const int B = 8192;
  const size_t BD = (size_t)B * 1024;
  char* ws = (char*)d_ws;

  // ---- arena: persistent region -------------------------------------------
  size_t o = 0;
  auto take = [&](size_t bytes) { size_t r = o; o = (o + bytes + 255) & ~(size_t)255; return r; };
  const size_t off_s1t  = take((size_t)512 * 128 * 2);
  const size_t off_s2t  = take((size_t)512 * 512 * 2);
  const size_t off_s3t  = take((size_t)1024 * 512 * 2);
  const size_t off_tWt  = take((size_t)1024 * 64 * 2);
  const size_t off_rdt  = take((size_t)2 * 64 * 1024 * 2);
  const size_t off_rut  = take((size_t)1024 * 64 * 2);
  const size_t off_eWt  = take((size_t)16 * 1024 * 1024 * 2);
  const size_t off_fobs = take(BD * 2);
  const size_t off_probs= take((size_t)2 * B * 64 * 4);
  const size_t off_Wh   = take((size_t)9 * 8192 * 2);
  const size_t P0 = o;
  // ---- scratch overlays (routing phase) -----------------------------------
  const size_t off_rin  = P0;                 // also h1
  const size_t off_rbuf = off_rin + BD * 2;   // also h2, u
  const size_t off_pbuf = off_rbuf + BD * 2;
  const size_t off_pbf  = off_pbuf + (size_t)2 * B * 64 * 4;
  const size_t off_obs  = off_pbf + (size_t)B * 64 * 2;
  const size_t off_task = off_obs + (size_t)B * 128 * 2;
  const size_t routing_end = off_task + (size_t)B * 64 * 2;

  // ---- expert-stage chunk selection (he/xx overlay scratch at P0) ---------
  int chunk = 0;
  const int cands[4] = {8192, 4096, 2048, 1024};
  for (int i = 0; i < 4; ++i) {
    size_t need = P0 + (size_t)cands[i] * 32768;  // he + xx
    if (need <= ws_size) { chunk = cands[i]; break; }
  }
  if (!chunk || routing_end > ws_size) return;

  us* s1t  = (us*)(ws + off_s1t);
  us* s2t  = (us*)(ws + off_s2t);
  us* s3t  = (us*)(ws + off_s3t);
  us* tWt  = (us*)(ws + off_tWt);
  us* rdt  = (us*)(ws + off_rdt);
  us* rut  = (us*)(ws + off_rut);
  us* eWt  = (us*)(ws + off_eWt);
  us* fobs = (us*)(ws + off_fobs);
  float* probs = (float*)(ws + off_probs);
  us* Wh   = (us*)(ws + off_Wh);
  us* rin  = (us*)(ws + off_rin);
  us* rbuf = (us*)(ws + off_rbuf);
  float* pbuf = (float*)(ws + off_pbuf);
  us* pbf  = (us*)(ws + off_pbf);
  us* obs_bf  = (us*)(ws + off_obs);
  us* task_bf = (us*)(ws + off_task);
  us* h1 = rin;
  us* h2 = rbuf;
  us* he = (us*)(ws + P0);
  us* xx = (us*)(ws + P0 + (size_t)chunk * 16384);  // also b-major for head

  // ---- fused prep: transposes + Wh + pbuf zero + out bias + x split -------
  // blocks: 64+256+512+64+128+64+16384+288+4096+288+6144 = 28288
  prep_kernel<<<dim3(28288), 256, 0, stream>>>(x, sW1, sW2, sW3, tW, rdW, ruW,
      eW, aW, cW, ab, cb, obs_bf, task_bf, s1t, s2t, s3t, tWt, rdt, rut,
      eWt, Wh, pbuf, out);

  // ---- shared MLP ---------------------------------------------------------
  gemm_bt<<<dim3(4, 64, 1), 256, 0, stream>>>(obs_bf, s1t, sb1, h1, (us*)0,
      (float*)0, (const us*)0, B, 512, 128, 128, 128, 0, 0, 0, 0, 1, 0, 0, 0, 0, 0);
  gemm_bt<<<dim3(4, 64, 1), 256, 0, stream>>>(h1, s2t, sb2, h2, (us*)0,
      (float*)0, (const us*)0, B, 512, 512, 512, 512, 0, 0, 0, 0, 1, 0, 0, 0, 0, 0);
  gemm_bt<<<dim3(8, 64, 1), 256, 0, stream>>>(h2, s3t, sb3, fobs, (us*)0,
      (float*)0, (const us*)0, B, 1024, 512, 512, 512, 0, 0, 0, 0, 0, 0, 0, 0, 0, 0);
  // z-GEMM fused: rin = relu(task@tW+tb)*fobs ; rbuf = relu(rin)
  gemm_bt<<<dim3(8, 64, 1), 256, 0, stream>>>(task_bf, tWt, tb, rin, rbuf,
      (float*)0, fobs, B, 1024, 64, 64, 64, 0, 0, 0, 0, 1, 0, 0, 0, 0, 0);

  // ---- routing (layers 0,1; layer 2 is dead code) -------------------------
  gemm_bt<<<dim3(1, 64, 4), 256, 0, stream>>>(rbuf, rdt, (const float*)0,
      (us*)0, (us*)0, pbuf, (const us*)0,
      B, 64, 256, 1024, 1024, 256, 256, 0, 0, 0, 0, 1, 0, 0, 0);   // p0 split-K
  mk_pbf<<<dim3((B * 64 + 255) / 256), 256, 0, stream>>>(pbuf, rdb, pbf, B * 64);
  // u-GEMM fused: rbuf = relu((pbf@ruW+rub) * rin)
  gemm_bt<<<dim3(8, 64, 1), 256, 0, stream>>>(pbf, rut, rub, rbuf, (us*)0,
      (float*)0, rin, B, 1024, 64, 64, 64, 0, 0, 0, 0, 0, 1, 0, 0, 0, 0);
  gemm_bt<<<dim3(1, 64, 4), 256, 0, stream>>>(rbuf, rdt + 65536, (const float*)0,
      (us*)0, (us*)0, pbuf + (size_t)B * 64, (const us*)0,
      B, 64, 256, 1024, 1024, 256, 256, 0, 0, 0, 0, 1, 0, 0, 0);   // p1 split-K
  // softmax; p1 half gets its rdb bias applied inline
  softmax8_kernel<<<dim3((2 * B * 8 + 255) / 256), 256, 0, stream>>>(
      pbuf, probs, rdb + 64, B * 8, 2 * B * 8);

  // ---- expert stage, chunked over batch -----------------------------------
  const long long sHE = (long long)chunk * 1024;
  for (int b0 = 0; b0 < B; b0 += chunk) {
    gemm_bt<<<dim3(8, chunk / 128, 8), 256, 0, stream>>>(
        fobs + (size_t)b0 * 1024, eWt, eb, he, (us*)0, (float*)0, (const us*)0,
        chunk, 1024, 1024, 1024, 1024, 0, 1048576, 1024, sHE, 1, 0, 0, 0, 0, 0);
    mix_kernel<<<dim3(chunk), 256, 0, stream>>>(he, probs, xx, b0, chunk, sHE, 1024);
    gemm_bt<<<dim3(8, chunk / 128, 8), 256, 0, stream>>>(
        xx, eWt + (size_t)8 * 1048576, eb + 8192, he, (us*)0, (float*)0, (const us*)0,
        chunk, 1024, 1024, 1024, 1024, sHE, 1048576, 1024, sHE, 1, 0, 0, 0, 0, 0);
    // xx reused in b-major layout [bl][e*1024+d] for the head GEMM
    mix_kernel<<<dim3(chunk), 256, 0, stream>>>(he, probs + (size_t)B * 64, xx,
        b0, chunk, 1024, 8192);
    // heads: M=chunk, N=9, K=8192, split-K=4, atomic direct into out
    gemm_bt<<<dim3(1, chunk / 128, 4), 256, 0, stream>>>(
        xx, Wh, (const float*)0, (us*)0, (us*)0, out, (const us*)0,
        chunk, 9, 2048, 8192, 8192, 2048, 2048, 0, 0, 0, 0, 1, 1, b0, B);
  }
}

// Round 7
// 839.548 us; speedup vs baseline: 1.0603x; 1.0603x over previous
//
#include <hip/hip_runtime.h>

// ---------------------------------------------------------------------------
// SharedPPOSoftModularizedMLP on MI355X (gfx950)
// B=8192, OBS=128, TASK=64, D=1024, E=8, L=4
// bf16 MFMA (16x16x32), fp32 accumulate.
// R7: specialize the GEMM. gemm_main<BIAS,RELU,MUL,RELU2,CB2> (bf16 vecpath
//     only, no clamp/atomic/headout dead code -> VGPR down, occupancy up);
//     gemm_splitk for the three small atomic dispatches (p0/p1/head).
// ---------------------------------------------------------------------------

typedef __attribute__((ext_vector_type(8))) short short8;   // 8 x bf16 frag
typedef __attribute__((ext_vector_type(4))) float floatx4;  // MFMA acc
typedef unsigned short us;

__device__ __forceinline__ us f2bf(float f) {
  union { float f; unsigned u; } v; v.f = f;
  return (us)((v.u + 0x7FFFu + ((v.u >> 16) & 1u)) >> 16);  // RNE
}
__device__ __forceinline__ float bf2f(us h) {
  union { unsigned u; float f; } v; v.u = ((unsigned)h) << 16;
  return v.f;
}

// async global->LDS, 16B per lane; lds dest = wave-uniform base + lane*16
__device__ __forceinline__ void g2lds16(const void* g, void* l) {
  __builtin_amdgcn_global_load_lds(
      (const __attribute__((address_space(1))) void*)g,
      (__attribute__((address_space(3))) void*)l, 16, 0, 0);
}

// ---------------------------------------------------------------------------
// Main-path GEMM: C[M,N] = post(act(A@Bt^T + bias)); all bf16, M,N %128==0.
// post: MUL -> elementwise * Mul[M,N]; RELU2 -> relu after MUL.
// CB2: Cb = value, Cb2 = relu(value).
// grid=(N/128, M/128, E). XCD chunk swizzle when total blocks % 8 == 0.
// ---------------------------------------------------------------------------
template<bool BIAS, bool RELU, bool MUL, bool RELU2, bool CB2>
__global__ __launch_bounds__(256)
void gemm_main(const us* __restrict__ A, const us* __restrict__ Bt,
               const float* __restrict__ bias,
               us* __restrict__ Cb, us* __restrict__ Cb2,
               const us* __restrict__ Mul,
               int N, int K, int lda, int ldb,
               long long sA, long long sB, long long sBias, long long sC)
{
  // ---- XCD chunk swizzle ----
  int bx = blockIdx.x, by = blockIdx.y, bz = blockIdx.z;
  {
    const int gx = gridDim.x, gy = gridDim.y;
    const int total = gx * gy * gridDim.z;
    if ((total & 7) == 0) {
      int L = bx + gx * (by + gy * bz);
      int per = total >> 3;
      int w = (L & 7) * per + (L >> 3);
      bx = w % gx; w /= gx;
      by = w % gy; bz = w / gy;
    }
  }

  const int e = bz;
  const us* Ab = A + (size_t)e * sA;
  const us* Bb = Bt + (size_t)e * sB;

  const int m0 = by * 128;
  const int n0 = bx * 128;
  const int tid = threadIdx.x;
  const int wave = tid >> 6;
  const int lane = tid & 63;
  const int wm = (wave >> 1) * 64;
  const int wn = (wave & 1) * 64;
  const int lr = lane & 15;
  const int lq = lane >> 4;

  // 32768 B exactly: staging A|B (2 x 8192 us) OR epilogue tile (128x128 us)
  __shared__ __align__(16) us smem[128 * 128];
  us* ldsA = smem;
  us* ldsB = smem + 128 * 64;

  floatx4 acc[4][4];
#pragma unroll
  for (int i = 0; i < 4; ++i)
#pragma unroll
    for (int j = 0; j < 4; ++j) acc[i][j] = (floatx4){0.f, 0.f, 0.f, 0.f};

  for (int k0 = 0; k0 < K; k0 += 64) {
#pragma unroll
    for (int c = 0; c < 4; ++c) {
      int slot = c * 256 + tid;               // physical 16B chunk
      int r = slot >> 3;
      int s = (slot & 7) ^ (r & 7);           // logical slab (XOR swizzle)
      int ubase = (c * 256 + wave * 64) * 8;  // wave-uniform LDS base (us)
      g2lds16(Ab + (size_t)(m0 + r) * lda + k0 + s * 8, ldsA + ubase);
      g2lds16(Bb + (size_t)(n0 + r) * ldb + k0 + s * 8, ldsB + ubase);
    }
    __syncthreads();

#pragma unroll
    for (int kk = 0; kk < 2; ++kk) {
      short8 af[4], bfr[4];
#pragma unroll
      for (int t = 0; t < 4; ++t) {
        int m = wm + t * 16 + lr;
        int s = kk * 4 + lq;
        af[t]  = *(const short8*)(ldsA + (size_t)(m * 8 + (s ^ (m & 7))) * 8);
        int n = wn + t * 16 + lr;
        bfr[t] = *(const short8*)(ldsB + (size_t)(n * 8 + (s ^ (n & 7))) * 8);
      }
#pragma unroll
      for (int mt = 0; mt < 4; ++mt)
#pragma unroll
        for (int nt = 0; nt < 4; ++nt)
          acc[mt][nt] = __builtin_amdgcn_mfma_f32_16x16x32_bf16(
              af[mt], bfr[nt], acc[mt][nt], 0, 0, 0);
    }
    __syncthreads();
  }

  // ---- epilogue: stage bf16 tile in LDS (seg-XOR, stride 128), store x4 ----
  // C/D layout: col = lane&15, row = lq*4 + r
#pragma unroll
  for (int nt = 0; nt < 4; ++nt) {
    int coll = wn + nt * 16 + lr;
    int col = n0 + coll;
    int seg = coll >> 3, cw = coll & 7;
    float bv = BIAS ? bias[(size_t)e * sBias + col] : 0.f;
#pragma unroll
    for (int mt = 0; mt < 4; ++mt) {
      int rowb = wm + mt * 16 + lq * 4;
#pragma unroll
      for (int r = 0; r < 4; ++r) {
        int rowl = rowb + r;
        float v = acc[mt][nt][r] + bv;
        if (RELU) v = fmaxf(v, 0.f);
        if (MUL) v *= bf2f(Mul[(size_t)(m0 + rowl) * N + col]);
        if (RELU2) v = fmaxf(v, 0.f);
        smem[rowl * 128 + ((seg ^ (rowl & 7)) << 3) + cw] = f2bf(v);
      }
    }
  }
  __syncthreads();
#pragma unroll
  for (int c = 0; c < 8; ++c) {
    int sl = c * 256 + tid;
    int rowl = sl >> 4;
    int seg = sl & 15;
    short8 val = *(const short8*)(smem + rowl * 128 + ((seg ^ (rowl & 7)) << 3));
    size_t gidx = (size_t)e * sC + (size_t)(m0 + rowl) * N + n0 + seg * 8;
    *(short8*)(Cb + gidx) = val;
    if (CB2) {
      short8 rl;
#pragma unroll
      for (int q = 0; q < 8; ++q) {
        us u = (us)val[q];
        rl[q] = (short)((u & 0x8000u) ? (us)0 : u);
      }
      *(short8*)(Cb2 + gidx) = rl;
    }
  }
}

// ---------------------------------------------------------------------------
// Split-K GEMM: atomicAdd fp32 partials.  blockIdx.z = k-chunk (offset by
// sA/sB).  N may be < 128 (B-row clamp).  headout remaps columns:
//   col<8 -> Cf[(rowoff+row)*8+col], col==8 -> Cf[Btot*8+rowoff+row].
// Used for p0/p1 (N=64) and the head GEMM (N=9) only.
// ---------------------------------------------------------------------------
__global__ __launch_bounds__(256)
void gemm_splitk(const us* __restrict__ A, const us* __restrict__ Bt,
                 float* __restrict__ Cf,
                 int N, int K, int lda, int ldb,
                 long long sA, long long sB,
                 int headout, int rowoff, int Btot)
{
  int bx = blockIdx.x, by = blockIdx.y, bz = blockIdx.z;
  {
    const int gx = gridDim.x, gy = gridDim.y;
    const int total = gx * gy * gridDim.z;
    if ((total & 7) == 0) {
      int L = bx + gx * (by + gy * bz);
      int per = total >> 3;
      int w = (L & 7) * per + (L >> 3);
      bx = w % gx; w /= gx;
      by = w % gy; bz = w / gy;
    }
  }

  const us* Ab = A + (size_t)bz * sA;
  const us* Bb = Bt + (size_t)bz * sB;

  const int m0 = by * 128;
  const int n0 = bx * 128;
  const int tid = threadIdx.x;
  const int wave = tid >> 6;
  const int lane = tid & 63;
  const int wm = (wave >> 1) * 64;
  const int wn = (wave & 1) * 64;
  const int lr = lane & 15;
  const int lq = lane >> 4;

  __shared__ __align__(16) us smem[128 * 128];
  us* ldsA = smem;
  us* ldsB = smem + 128 * 64;

  floatx4 acc[4][4];
#pragma unroll
  for (int i = 0; i < 4; ++i)
#pragma unroll
    for (int j = 0; j < 4; ++j) acc[i][j] = (floatx4){0.f, 0.f, 0.f, 0.f};

  for (int k0 = 0; k0 < K; k0 += 64) {
#pragma unroll
    for (int c = 0; c < 4; ++c) {
      int slot = c * 256 + tid;
      int r = slot >> 3;
      int s = (slot & 7) ^ (r & 7);
      int ubase = (c * 256 + wave * 64) * 8;
      g2lds16(Ab + (size_t)(m0 + r) * lda + k0 + s * 8, ldsA + ubase);
      int nrow = n0 + r; if (nrow > N - 1) nrow = N - 1;  // clamp (N<128)
      g2lds16(Bb + (size_t)nrow * ldb + k0 + s * 8, ldsB + ubase);
    }
    __syncthreads();

#pragma unroll
    for (int kk = 0; kk < 2; ++kk) {
      short8 af[4], bfr[4];
#pragma unroll
      for (int t = 0; t < 4; ++t) {
        int m = wm + t * 16 + lr;
        int s = kk * 4 + lq;
        af[t]  = *(const short8*)(ldsA + (size_t)(m * 8 + (s ^ (m & 7))) * 8);
        int n = wn + t * 16 + lr;
        bfr[t] = *(const short8*)(ldsB + (size_t)(n * 8 + (s ^ (n & 7))) * 8);
      }
#pragma unroll
      for (int mt = 0; mt < 4; ++mt)
#pragma unroll
        for (int nt = 0; nt < 4; ++nt)
          acc[mt][nt] = __builtin_amdgcn_mfma_f32_16x16x32_bf16(
              af[mt], bfr[nt], acc[mt][nt], 0, 0, 0);
    }
    __syncthreads();
  }

#pragma unroll
  for (int nt = 0; nt < 4; ++nt) {
    int col = n0 + wn + nt * 16 + lr;
    if (col >= N) continue;
#pragma unroll
    for (int mt = 0; mt < 4; ++mt) {
      int row = m0 + wm + mt * 16 + lq * 4;
#pragma unroll
      for (int r = 0; r < 4; ++r) {
        float v = acc[mt][nt][r];
        if (headout) {
          size_t di = (col < 8) ? ((size_t)(rowoff + row + r) * 8 + col)
                                : ((size_t)Btot * 8 + rowoff + row + r);
          atomicAdd(Cf + di, v);
        } else {
          atomicAdd(Cf + (size_t)(row + r) * N + col, v);
        }
      }
    }
  }
}

// ---------------------------------------------------------------------------
// Fused prep: all weight transposes (fp32 [R,C] -> bf16 [C,R]), Wh build,
// pbuf zero, out bias init, x split/convert.  One launch, range ladder.
// ---------------------------------------------------------------------------
__device__ __forceinline__ void transpose_tile(
    const float* __restrict__ in, us* __restrict__ out,
    int R, int C, int bx, int by, float (*tile)[33])
{
  const int tx = threadIdx.x & 31, ty = threadIdx.x >> 5;
  const int c0 = bx * 32, r0 = by * 32;
#pragma unroll
  for (int i = 0; i < 4; ++i) {
    int r = r0 + ty + i * 8, c = c0 + tx;
    tile[ty + i * 8][tx] = (r < R && c < C) ? in[(size_t)r * C + c] : 0.f;
  }
  __syncthreads();
#pragma unroll
  for (int i = 0; i < 4; ++i) {
    int c = c0 + ty + i * 8, r = r0 + tx;
    if (c < C && r < R) out[(size_t)c * R + r] = f2bf(tile[tx][ty + i * 8]);
  }
}

__global__ __launch_bounds__(256)
void prep_kernel(const float* __restrict__ x,
                 const float* __restrict__ sW1, const float* __restrict__ sW2,
                 const float* __restrict__ sW3, const float* __restrict__ tW,
                 const float* __restrict__ rdW, const float* __restrict__ ruW,
                 const float* __restrict__ eW,
                 const float* __restrict__ aW, const float* __restrict__ cW,
                 const float* __restrict__ ab, const float* __restrict__ cb,
                 us* __restrict__ obs, us* __restrict__ task,
                 us* __restrict__ s1t, us* __restrict__ s2t,
                 us* __restrict__ s3t, us* __restrict__ tWt,
                 us* __restrict__ rdt, us* __restrict__ rut,
                 us* __restrict__ eWt, us* __restrict__ Wh,
                 float* __restrict__ pbuf, float* __restrict__ out)
{
  __shared__ float tile[32][33];
  int b = blockIdx.x;
  const int tid = threadIdx.x;

  if (b < 64)  { transpose_tile(sW1, s1t, 128, 512, b % 16, b / 16, tile); return; }
  b -= 64;
  if (b < 256) { transpose_tile(sW2, s2t, 512, 512, b % 16, b / 16, tile); return; }
  b -= 256;
  if (b < 512) { transpose_tile(sW3, s3t, 512, 1024, b % 32, b / 32, tile); return; }
  b -= 512;
  if (b < 64)  { transpose_tile(tW, tWt, 64, 1024, b % 32, b / 32, tile); return; }
  b -= 64;
  if (b < 128) { int l = b >> 6, r = b & 63;
                 transpose_tile(rdW + (size_t)l * 65536, rdt + (size_t)l * 65536,
                                1024, 64, r % 2, r / 2, tile); return; }
  b -= 128;
  if (b < 64)  { transpose_tile(ruW, rut, 64, 1024, b % 32, b / 32, tile); return; }
  b -= 64;
  if (b < 16384) { int l = b >> 10, r = b & 1023;
                 transpose_tile(eW + (size_t)l * 1048576, eWt + (size_t)l * 1048576,
                                1024, 1024, r % 32, r / 32, tile); return; }
  b -= 16384;
  if (b < 288) {  // Wh[o][e*1024+d] = aW[e][d][o] (o<8) | cW[e][d]
    int i = b * 256 + tid;
    int o = i / 8192, k = i - o * 8192;
    float v = (o < 8) ? aW[(size_t)k * 8 + o] : cW[k];
    Wh[i] = f2bf(v);
    return;
  }
  b -= 288;
  if (b < 4096) { pbuf[(size_t)b * 256 + tid] = 0.f; return; }
  b -= 4096;
  if (b < 288) {  // out bias init: mu gets sum_e ab, values gets sum_e cb
    int i = b * 256 + tid;
    int bb = i / 9, o = i - bb * 9;
    float s = 0.f;
    if (o < 8) { for (int e = 0; e < 8; ++e) s += ab[e * 8 + o]; }
    else       { for (int e = 0; e < 8; ++e) s += cb[e]; }
    if (o < 8) out[(size_t)bb * 8 + o] = s;
    else       out[(size_t)8192 * 8 + bb] = s;
    return;
  }
  b -= 288;
  {  // split x(B,192) -> obs (B,128), task (B,64)
    int i = b * 256 + tid;
    int bb = i / 192, c = i - bb * 192;
    us v = f2bf(x[i]);
    if (c < 128) obs[(size_t)bb * 128 + c] = v;
    else         task[(size_t)bb * 64 + (c - 128)] = v;
  }
}

// pbuf[i] += rdb[i&63]; pbf[i] = bf16(pbuf[i])
__global__ __launch_bounds__(256)
void mk_pbf(float* __restrict__ pbuf, const float* __restrict__ rdb,
            us* __restrict__ pbf, int n)
{
  int i = blockIdx.x * 256 + threadIdx.x;
  if (i >= n) return;
  float v = pbuf[i] + rdb[i & 63];
  pbuf[i] = v;
  if (pbf) pbf[i] = f2bf(v);
}

// softmax over groups of 8; groups i >= biasFrom get +bias2[(i&7)*8+j] first
__global__ __launch_bounds__(256)
void softmax8_kernel(const float* __restrict__ p, float* __restrict__ probs,
                     const float* __restrict__ bias2, int biasFrom, int total)
{
  int i = blockIdx.x * 256 + threadIdx.x;
  if (i >= total) return;
  const float4 lo = *(const float4*)(p + (size_t)i * 8);
  const float4 hi = *(const float4*)(p + (size_t)i * 8 + 4);
  float v[8] = { lo.x, lo.y, lo.z, lo.w, hi.x, hi.y, hi.z, hi.w };
  if (i >= biasFrom) {
    const float* bb = bias2 + (i & 7) * 8;
#pragma unroll
    for (int j = 0; j < 8; ++j) v[j] += bb[j];
  }
  float m = v[0];
#pragma unroll
  for (int j = 1; j < 8; ++j) m = fmaxf(m, v[j]);
  float s = 0.f;
#pragma unroll
  for (int j = 0; j < 8; ++j) { v[j] = __expf(v[j] - m); s += v[j]; }
  float inv = 1.f / s;
  float4 olo = { v[0]*inv, v[1]*inv, v[2]*inv, v[3]*inv };
  float4 ohi = { v[4]*inv, v[5]*inv, v[6]*inv, v[7]*inv };
  *(float4*)(probs + (size_t)i * 8)     = olo;
  *(float4*)(probs + (size_t)i * 8 + 4) = ohi;
}

// out[i*sOutE + bl*sOutB + d] = sum_j P[bg,i,j]*he[j,bl,d]; block per local b
__global__ __launch_bounds__(256)
void mix_kernel(const us* __restrict__ he, const float* __restrict__ probs_l,
                us* __restrict__ xx, int b0, int chunkB,
                long long sOutE, long long sOutB)
{
  const int bl = blockIdx.x;
  const int bg = b0 + bl;
  __shared__ float P[64];
  if (threadIdx.x < 64) P[threadIdx.x] = probs_l[(size_t)bg * 64 + threadIdx.x];
  __syncthreads();
  const int t = threadIdx.x;
  const size_t es = (size_t)chunkB * 1024;
  const size_t rbase = (size_t)bl * 1024 + (size_t)t * 4;
  const size_t wbase = (size_t)bl * sOutB + (size_t)t * 4;
  float hv[8][4];
#pragma unroll
  for (int j = 0; j < 8; ++j) {
    ushort4 h4 = *(const ushort4*)(he + (size_t)j * es + rbase);
    hv[j][0] = bf2f(h4.x); hv[j][1] = bf2f(h4.y);
    hv[j][2] = bf2f(h4.z); hv[j][3] = bf2f(h4.w);
  }
#pragma unroll
  for (int i = 0; i < 8; ++i) {
    float o0 = 0.f, o1 = 0.f, o2 = 0.f, o3 = 0.f;
#pragma unroll
    for (int j = 0; j < 8; ++j) {
      float pij = P[i * 8 + j];
      o0 += pij * hv[j][0]; o1 += pij * hv[j][1];
      o2 += pij * hv[j][2]; o3 += pij * hv[j][3];
    }
    ushort4 ov = { f2bf(o0), f2bf(o1), f2bf(o2), f2bf(o3) };
    *(ushort4*)(xx + (size_t)i * sOutE + wbase) = ov;
  }
}

// ---------------------------------------------------------------------------
extern "C" void kernel_launch(void* const* d_in, const int* in_sizes, int n_in,
                              void* d_out, int out_size, void* d_ws, size_t ws_size,
                              hipStream_t stream)
{
  const float* x   = (const float*)d_in[0];
  const float* sW1 = (const float*)d_in[1];
  const float* sb1 = (const float*)d_in[2];
  const float* sW2 = (const float*)d_in[3];
  const float* sb2 = (const float*)d_in[4];
  const float* sW3 = (const float*)d_in[5];
  const float* sb3 = (const float*)d_in[6];
  const float* tW  = (const float*)d_in[7];
  const float* tb  = (const float*)d_in[8];
  const float* rdW = (const float*)d_in[9];
  const float* rdb = (const float*)d_in[10];
  const float* ruW = (const float*)d_in[11];
  const float* rub = (const float*)d_in[12];
  const float* eW  = (const float*)d_in[13];
  const float* eb  = (const float*)d_in[14];
  const float* aW  = (const float*)d_in[15];
  const float* ab  = (const float*)d_in[16];
  const float* cW  = (const float*)d_in[17];
  const float* cb  = (const float*)d_in[18];
  float* out = (float*)d_out;

  const int B = 8192;
  const size_t BD = (size_t)B * 1024;
  char* ws = (char*)d_ws;

  // ---- arena: persistent region -------------------------------------------
  size_t o = 0;
  auto take = [&](size_t bytes) { size_t r = o; o = (o + bytes + 255) & ~(size_t)255; return r; };
  const size_t off_s1t  = take((size_t)512 * 128 * 2);
  const size_t off_s2t  = take((size_t)512 * 512 * 2);
  const size_t off_s3t  = take((size_t)1024 * 512 * 2);
  const size_t off_tWt  = take((size_t)1024 * 64 * 2);
  const size_t off_rdt  = take((size_t)2 * 64 * 1024 * 2);
  const size_t off_rut  = take((size_t)1024 * 64 * 2);
  const size_t off_eWt  = take((size_t)16 * 1024 * 1024 * 2);
  const size_t off_fobs = take(BD * 2);
  const size_t off_probs= take((size_t)2 * B * 64 * 4);
  const size_t off_Wh   = take((size_t)9 * 8192 * 2);
  const size_t P0 = o;
  // ---- scratch overlays (routing phase) -----------------------------------
  const size_t off_rin  = P0;                 // also h1
  const size_t off_rbuf = off_rin + BD * 2;   // also h2, u
  const size_t off_pbuf = off_rbuf + BD * 2;
  const size_t off_pbf  = off_pbuf + (size_t)2 * B * 64 * 4;
  const size_t off_obs  = off_pbf + (size_t)B * 64 * 2;
  const size_t off_task = off_obs + (size_t)B * 128 * 2;
  const size_t routing_end = off_task + (size_t)B * 64 * 2;

  // ---- expert-stage chunk selection (he/xx overlay scratch at P0) ---------
  int chunk = 0;
  const int cands[4] = {8192, 4096, 2048, 1024};
  for (int i = 0; i < 4; ++i) {
    size_t need = P0 + (size_t)cands[i] * 32768;  // he + xx
    if (need <= ws_size) { chunk = cands[i]; break; }
  }
  if (!chunk || routing_end > ws_size) return;

  us* s1t  = (us*)(ws + off_s1t);
  us* s2t  = (us*)(ws + off_s2t);
  us* s3t  = (us*)(ws + off_s3t);
  us* tWt  = (us*)(ws + off_tWt);
  us* rdt  = (us*)(ws + off_rdt);
  us* rut  = (us*)(ws + off_rut);
  us* eWt  = (us*)(ws + off_eWt);
  us* fobs = (us*)(ws + off_fobs);
  float* probs = (float*)(ws + off_probs);
  us* Wh   = (us*)(ws + off_Wh);
  us* rin  = (us*)(ws + off_rin);
  us* rbuf = (us*)(ws + off_rbuf);
  float* pbuf = (float*)(ws + off_pbuf);
  us* pbf  = (us*)(ws + off_pbf);
  us* obs_bf  = (us*)(ws + off_obs);
  us* task_bf = (us*)(ws + off_task);
  us* h1 = rin;
  us* h2 = rbuf;
  us* he = (us*)(ws + P0);
  us* xx = (us*)(ws + P0 + (size_t)chunk * 16384);  // also b-major for head

  // ---- fused prep: transposes + Wh + pbuf zero + out bias + x split -------
  prep_kernel<<<dim3(28288), 256, 0, stream>>>(x, sW1, sW2, sW3, tW, rdW, ruW,
      eW, aW, cW, ab, cb, obs_bf, task_bf, s1t, s2t, s3t, tWt, rdt, rut,
      eWt, Wh, pbuf, out);

  // ---- shared MLP ---------------------------------------------------------
  gemm_main<true, true, false, false, false><<<dim3(4, 64, 1), 256, 0, stream>>>(
      obs_bf, s1t, sb1, h1, (us*)0, (const us*)0, 512, 128, 128, 128, 0, 0, 0, 0);
  gemm_main<true, true, false, false, false><<<dim3(4, 64, 1), 256, 0, stream>>>(
      h1, s2t, sb2, h2, (us*)0, (const us*)0, 512, 512, 512, 512, 0, 0, 0, 0);
  gemm_main<true, false, false, false, false><<<dim3(8, 64, 1), 256, 0, stream>>>(
      h2, s3t, sb3, fobs, (us*)0, (const us*)0, 1024, 512, 512, 512, 0, 0, 0, 0);
  // z-GEMM fused: rin = relu(task@tW+tb)*fobs ; rbuf = relu(rin)
  gemm_main<true, true, true, false, true><<<dim3(8, 64, 1), 256, 0, stream>>>(
      task_bf, tWt, tb, rin, rbuf, fobs, 1024, 64, 64, 64, 0, 0, 0, 0);

  // ---- routing (layers 0,1; layer 2 is dead code) -------------------------
  gemm_splitk<<<dim3(1, 64, 4), 256, 0, stream>>>(rbuf, rdt, pbuf,
      64, 256, 1024, 1024, 256, 256, 0, 0, 0);                       // p0
  mk_pbf<<<dim3((B * 64 + 255) / 256), 256, 0, stream>>>(pbuf, rdb, pbf, B * 64);
  // u-GEMM fused: rbuf = relu((pbf@ruW+rub) * rin)
  gemm_main<true, false, true, true, false><<<dim3(8, 64, 1), 256, 0, stream>>>(
      pbf, rut, rub, rbuf, (us*)0, rin, 1024, 64, 64, 64, 0, 0, 0, 0);
  gemm_splitk<<<dim3(1, 64, 4), 256, 0, stream>>>(rbuf, rdt + 65536,
      pbuf + (size_t)B * 64, 64, 256, 1024, 1024, 256, 256, 0, 0, 0); // p1
  softmax8_kernel<<<dim3((2 * B * 8 + 255) / 256), 256, 0, stream>>>(
      pbuf, probs, rdb + 64, B * 8, 2 * B * 8);

  // ---- expert stage, chunked over batch -----------------------------------
  const long long sHE = (long long)chunk * 1024;
  for (int b0 = 0; b0 < B; b0 += chunk) {
    gemm_main<true, true, false, false, false><<<dim3(8, chunk / 128, 8), 256, 0, stream>>>(
        fobs + (size_t)b0 * 1024, eWt, eb, he, (us*)0, (const us*)0,
        1024, 1024, 1024, 1024, 0, 1048576, 1024, sHE);
    mix_kernel<<<dim3(chunk), 256, 0, stream>>>(he, probs, xx, b0, chunk, sHE, 1024);
    gemm_main<true, true, false, false, false><<<dim3(8, chunk / 128, 8), 256, 0, stream>>>(
        xx, eWt + (size_t)8 * 1048576, eb + 8192, he, (us*)0, (const us*)0,
        1024, 1024, 1024, 1024, sHE, 1048576, 1024, sHE);
    // xx reused in b-major layout [bl][e*1024+d] for the head GEMM
    mix_kernel<<<dim3(chunk), 256, 0, stream>>>(he, probs + (size_t)B * 64, xx,
        b0, chunk, 1024, 8192);
    // heads: M=chunk, N=9, K=8192, split-K=4, atomic direct into out
    gemm_splitk<<<dim3(1, chunk / 128, 4), 256, 0, stream>>>(
        xx, Wh, out, 9, 2048, 8192, 8192, 2048, 2048, 1, b0, B);
  }
}

// Round 8
// 770.747 us; speedup vs baseline: 1.1550x; 1.0893x over previous
//
#include <hip/hip_runtime.h>

// ---------------------------------------------------------------------------
// SharedPPOSoftModularizedMLP on MI355X (gfx950)
// B=8192, OBS=128, TASK=64, D=1024, E=8, L=4
// bf16 MFMA (16x16x32), fp32 accumulate.
// R8: restore R4's measured-best GEMM epilogue (stride-136 tile, no XOR --
//     VGPR 80 / 210us vs seg-XOR's 92 / 246us). Keep R7 specialization +
//     gemm_splitk + fused tail.
// ---------------------------------------------------------------------------

typedef __attribute__((ext_vector_type(8))) short short8;   // 8 x bf16 frag
typedef __attribute__((ext_vector_type(4))) float floatx4;  // MFMA acc
typedef unsigned short us;

__device__ __forceinline__ us f2bf(float f) {
  union { float f; unsigned u; } v; v.f = f;
  return (us)((v.u + 0x7FFFu + ((v.u >> 16) & 1u)) >> 16);  // RNE
}
__device__ __forceinline__ float bf2f(us h) {
  union { unsigned u; float f; } v; v.u = ((unsigned)h) << 16;
  return v.f;
}

// async global->LDS, 16B per lane; lds dest = wave-uniform base + lane*16
__device__ __forceinline__ void g2lds16(const void* g, void* l) {
  __builtin_amdgcn_global_load_lds(
      (const __attribute__((address_space(1))) void*)g,
      (__attribute__((address_space(3))) void*)l, 16, 0, 0);
}

// ---------------------------------------------------------------------------
// Main-path GEMM: C[M,N] = post(act(A@Bt^T + bias)); all bf16, M,N %128==0.
// post: MUL -> elementwise * Mul[M,N]; RELU2 -> relu after MUL.
// CB2: Cb = value, Cb2 = relu(value).
// grid=(N/128, M/128, E). XCD chunk swizzle when total blocks % 8 == 0.
// ---------------------------------------------------------------------------
template<bool BIAS, bool RELU, bool MUL, bool RELU2, bool CB2>
__global__ __launch_bounds__(256)
void gemm_main(const us* __restrict__ A, const us* __restrict__ Bt,
               const float* __restrict__ bias,
               us* __restrict__ Cb, us* __restrict__ Cb2,
               const us* __restrict__ Mul,
               int N, int K, int lda, int ldb,
               long long sA, long long sB, long long sBias, long long sC)
{
  // ---- XCD chunk swizzle ----
  int bx = blockIdx.x, by = blockIdx.y, bz = blockIdx.z;
  {
    const int gx = gridDim.x, gy = gridDim.y;
    const int total = gx * gy * gridDim.z;
    if ((total & 7) == 0) {
      int L = bx + gx * (by + gy * bz);
      int per = total >> 3;
      int w = (L & 7) * per + (L >> 3);
      bx = w % gx; w /= gx;
      by = w % gy; bz = w / gy;
    }
  }

  const int e = bz;
  const us* Ab = A + (size_t)e * sA;
  const us* Bb = Bt + (size_t)e * sB;

  const int m0 = by * 128;
  const int n0 = bx * 128;
  const int tid = threadIdx.x;
  const int wave = tid >> 6;
  const int lane = tid & 63;
  const int wm = (wave >> 1) * 64;
  const int wn = (wave & 1) * 64;
  const int lr = lane & 15;
  const int lq = lane >> 4;

  // staging: A = smem[0..8191], B = smem[8192..16383]  (us units)
  // epilogue tile: smem[0..17407] as [128][136] us  (R4 layout)
  __shared__ __align__(16) us smem[128 * 136 + 64];
  us* ldsA = smem;
  us* ldsB = smem + 128 * 64;

  floatx4 acc[4][4];
#pragma unroll
  for (int i = 0; i < 4; ++i)
#pragma unroll
    for (int j = 0; j < 4; ++j) acc[i][j] = (floatx4){0.f, 0.f, 0.f, 0.f};

  for (int k0 = 0; k0 < K; k0 += 64) {
#pragma unroll
    for (int c = 0; c < 4; ++c) {
      int slot = c * 256 + tid;               // physical 16B chunk
      int r = slot >> 3;
      int s = (slot & 7) ^ (r & 7);           // logical slab (XOR swizzle)
      int ubase = (c * 256 + wave * 64) * 8;  // wave-uniform LDS base (us)
      g2lds16(Ab + (size_t)(m0 + r) * lda + k0 + s * 8, ldsA + ubase);
      g2lds16(Bb + (size_t)(n0 + r) * ldb + k0 + s * 8, ldsB + ubase);
    }
    __syncthreads();

#pragma unroll
    for (int kk = 0; kk < 2; ++kk) {
      short8 af[4], bfr[4];
#pragma unroll
      for (int t = 0; t < 4; ++t) {
        int m = wm + t * 16 + lr;
        int s = kk * 4 + lq;
        af[t]  = *(const short8*)(ldsA + (size_t)(m * 8 + (s ^ (m & 7))) * 8);
        int n = wn + t * 16 + lr;
        bfr[t] = *(const short8*)(ldsB + (size_t)(n * 8 + (s ^ (n & 7))) * 8);
      }
#pragma unroll
      for (int mt = 0; mt < 4; ++mt)
#pragma unroll
        for (int nt = 0; nt < 4; ++nt)
          acc[mt][nt] = __builtin_amdgcn_mfma_f32_16x16x32_bf16(
              af[mt], bfr[nt], acc[mt][nt], 0, 0, 0);
    }
    __syncthreads();
  }

  // ---- epilogue (R4): stage bf16 tile in LDS [128][136], store dwordx4 ----
  // C/D layout: col = lane&15, row = lq*4 + r
#pragma unroll
  for (int nt = 0; nt < 4; ++nt) {
    int coll = wn + nt * 16 + lr;
    int col = n0 + coll;
    float bv = BIAS ? bias[(size_t)e * sBias + col] : 0.f;
#pragma unroll
    for (int mt = 0; mt < 4; ++mt) {
      int rowb = wm + mt * 16 + lq * 4;
#pragma unroll
      for (int r = 0; r < 4; ++r) {
        int rowl = rowb + r;
        float v = acc[mt][nt][r] + bv;
        if (RELU) v = fmaxf(v, 0.f);
        if (MUL) v *= bf2f(Mul[(size_t)(m0 + rowl) * N + col]);
        if (RELU2) v = fmaxf(v, 0.f);
        smem[rowl * 136 + coll] = f2bf(v);
      }
    }
  }
  __syncthreads();
#pragma unroll
  for (int c = 0; c < 8; ++c) {
    int sl = c * 256 + tid;
    int rowl = sl >> 4;
    int seg = sl & 15;
    short8 val = *(const short8*)(smem + rowl * 136 + seg * 8);
    size_t gidx = (size_t)e * sC + (size_t)(m0 + rowl) * N + n0 + seg * 8;
    *(short8*)(Cb + gidx) = val;
    if (CB2) {
      short8 rl;
#pragma unroll
      for (int q = 0; q < 8; ++q) {
        us u = (us)val[q];
        rl[q] = (short)((u & 0x8000u) ? (us)0 : u);
      }
      *(short8*)(Cb2 + gidx) = rl;
    }
  }
}

// ---------------------------------------------------------------------------
// Split-K GEMM: atomicAdd fp32 partials.  blockIdx.z = k-chunk (offset by
// sA/sB).  N may be < 128 (B-row clamp).  headout remaps columns:
//   col<8 -> Cf[(rowoff+row)*8+col], col==8 -> Cf[Btot*8+rowoff+row].
// Used for p0/p1 (N=64) and the head GEMM (N=9) only.
// ---------------------------------------------------------------------------
__global__ __launch_bounds__(256)
void gemm_splitk(const us* __restrict__ A, const us* __restrict__ Bt,
                 float* __restrict__ Cf,
                 int N, int K, int lda, int ldb,
                 long long sA, long long sB,
                 int headout, int rowoff, int Btot)
{
  int bx = blockIdx.x, by = blockIdx.y, bz = blockIdx.z;
  {
    const int gx = gridDim.x, gy = gridDim.y;
    const int total = gx * gy * gridDim.z;
    if ((total & 7) == 0) {
      int L = bx + gx * (by + gy * bz);
      int per = total >> 3;
      int w = (L & 7) * per + (L >> 3);
      bx = w % gx; w /= gx;
      by = w % gy; bz = w / gy;
    }
  }

  const us* Ab = A + (size_t)bz * sA;
  const us* Bb = Bt + (size_t)bz * sB;

  const int m0 = by * 128;
  const int n0 = bx * 128;
  const int tid = threadIdx.x;
  const int wave = tid >> 6;
  const int lane = tid & 63;
  const int wm = (wave >> 1) * 64;
  const int wn = (wave & 1) * 64;
  const int lr = lane & 15;
  const int lq = lane >> 4;

  __shared__ __align__(16) us smem[128 * 128];
  us* ldsA = smem;
  us* ldsB = smem + 128 * 64;

  floatx4 acc[4][4];
#pragma unroll
  for (int i = 0; i < 4; ++i)
#pragma unroll
    for (int j = 0; j < 4; ++j) acc[i][j] = (floatx4){0.f, 0.f, 0.f, 0.f};

  for (int k0 = 0; k0 < K; k0 += 64) {
#pragma unroll
    for (int c = 0; c < 4; ++c) {
      int slot = c * 256 + tid;
      int r = slot >> 3;
      int s = (slot & 7) ^ (r & 7);
      int ubase = (c * 256 + wave * 64) * 8;
      g2lds16(Ab + (size_t)(m0 + r) * lda + k0 + s * 8, ldsA + ubase);
      int nrow = n0 + r; if (nrow > N - 1) nrow = N - 1;  // clamp (N<128)
      g2lds16(Bb + (size_t)nrow * ldb + k0 + s * 8, ldsB + ubase);
    }
    __syncthreads();

#pragma unroll
    for (int kk = 0; kk < 2; ++kk) {
      short8 af[4], bfr[4];
#pragma unroll
      for (int t = 0; t < 4; ++t) {
        int m = wm + t * 16 + lr;
        int s = kk * 4 + lq;
        af[t]  = *(const short8*)(ldsA + (size_t)(m * 8 + (s ^ (m & 7))) * 8);
        int n = wn + t * 16 + lr;
        bfr[t] = *(const short8*)(ldsB + (size_t)(n * 8 + (s ^ (n & 7))) * 8);
      }
#pragma unroll
      for (int mt = 0; mt < 4; ++mt)
#pragma unroll
        for (int nt = 0; nt < 4; ++nt)
          acc[mt][nt] = __builtin_amdgcn_mfma_f32_16x16x32_bf16(
              af[mt], bfr[nt], acc[mt][nt], 0, 0, 0);
    }
    __syncthreads();
  }

#pragma unroll
  for (int nt = 0; nt < 4; ++nt) {
    int col = n0 + wn + nt * 16 + lr;
    if (col >= N) continue;
#pragma unroll
    for (int mt = 0; mt < 4; ++mt) {
      int row = m0 + wm + mt * 16 + lq * 4;
#pragma unroll
      for (int r = 0; r < 4; ++r) {
        float v = acc[mt][nt][r];
        if (headout) {
          size_t di = (col < 8) ? ((size_t)(rowoff + row + r) * 8 + col)
                                : ((size_t)Btot * 8 + rowoff + row + r);
          atomicAdd(Cf + di, v);
        } else {
          atomicAdd(Cf + (size_t)(row + r) * N + col, v);
        }
      }
    }
  }
}

// ---------------------------------------------------------------------------
// Fused prep: all weight transposes (fp32 [R,C] -> bf16 [C,R]), Wh build,
// pbuf zero, out bias init, x split/convert.  One launch, range ladder.
// ---------------------------------------------------------------------------
__device__ __forceinline__ void transpose_tile(
    const float* __restrict__ in, us* __restrict__ out,
    int R, int C, int bx, int by, float (*tile)[33])
{
  const int tx = threadIdx.x & 31, ty = threadIdx.x >> 5;
  const int c0 = bx * 32, r0 = by * 32;
#pragma unroll
  for (int i = 0; i < 4; ++i) {
    int r = r0 + ty + i * 8, c = c0 + tx;
    tile[ty + i * 8][tx] = (r < R && c < C) ? in[(size_t)r * C + c] : 0.f;
  }
  __syncthreads();
#pragma unroll
  for (int i = 0; i < 4; ++i) {
    int c = c0 + ty + i * 8, r = r0 + tx;
    if (c < C && r < R) out[(size_t)c * R + r] = f2bf(tile[tx][ty + i * 8]);
  }
}

__global__ __launch_bounds__(256)
void prep_kernel(const float* __restrict__ x,
                 const float* __restrict__ sW1, const float* __restrict__ sW2,
                 const float* __restrict__ sW3, const float* __restrict__ tW,
                 const float* __restrict__ rdW, const float* __restrict__ ruW,
                 const float* __restrict__ eW,
                 const float* __restrict__ aW, const float* __restrict__ cW,
                 const float* __restrict__ ab, const float* __restrict__ cb,
                 us* __restrict__ obs, us* __restrict__ task,
                 us* __restrict__ s1t, us* __restrict__ s2t,
                 us* __restrict__ s3t, us* __restrict__ tWt,
                 us* __restrict__ rdt, us* __restrict__ rut,
                 us* __restrict__ eWt, us* __restrict__ Wh,
                 float* __restrict__ pbuf, float* __restrict__ out)
{
  __shared__ float tile[32][33];
  int b = blockIdx.x;
  const int tid = threadIdx.x;

  if (b < 64)  { transpose_tile(sW1, s1t, 128, 512, b % 16, b / 16, tile); return; }
  b -= 64;
  if (b < 256) { transpose_tile(sW2, s2t, 512, 512, b % 16, b / 16, tile); return; }
  b -= 256;
  if (b < 512) { transpose_tile(sW3, s3t, 512, 1024, b % 32, b / 32, tile); return; }
  b -= 512;
  if (b < 64)  { transpose_tile(tW, tWt, 64, 1024, b % 32, b / 32, tile); return; }
  b -= 64;
  if (b < 128) { int l = b >> 6, r = b & 63;
                 transpose_tile(rdW + (size_t)l * 65536, rdt + (size_t)l * 65536,
                                1024, 64, r % 2, r / 2, tile); return; }
  b -= 128;
  if (b < 64)  { transpose_tile(ruW, rut, 64, 1024, b % 32, b / 32, tile); return; }
  b -= 64;
  if (b < 16384) { int l = b >> 10, r = b & 1023;
                 transpose_tile(eW + (size_t)l * 1048576, eWt + (size_t)l * 1048576,
                                1024, 1024, r % 32, r / 32, tile); return; }
  b -= 16384;
  if (b < 288) {  // Wh[o][e*1024+d] = aW[e][d][o] (o<8) | cW[e][d]
    int i = b * 256 + tid;
    int o = i / 8192, k = i - o * 8192;
    float v = (o < 8) ? aW[(size_t)k * 8 + o] : cW[k];
    Wh[i] = f2bf(v);
    return;
  }
  b -= 288;
  if (b < 4096) { pbuf[(size_t)b * 256 + tid] = 0.f; return; }
  b -= 4096;
  if (b < 288) {  // out bias init: mu gets sum_e ab, values gets sum_e cb
    int i = b * 256 + tid;
    int bb = i / 9, o = i - bb * 9;
    float s = 0.f;
    if (o < 8) { for (int e = 0; e < 8; ++e) s += ab[e * 8 + o]; }
    else       { for (int e = 0; e < 8; ++e) s += cb[e]; }
    if (o < 8) out[(size_t)bb * 8 + o] = s;
    else       out[(size_t)8192 * 8 + bb] = s;
    return;
  }
  b -= 288;
  {  // split x(B,192) -> obs (B,128), task (B,64)
    int i = b * 256 + tid;
    int bb = i / 192, c = i - bb * 192;
    us v = f2bf(x[i]);
    if (c < 128) obs[(size_t)bb * 128 + c] = v;
    else         task[(size_t)bb * 64 + (c - 128)] = v;
  }
}

// pbuf[i] += rdb[i&63]; pbf[i] = bf16(pbuf[i])
__global__ __launch_bounds__(256)
void mk_pbf(float* __restrict__ pbuf, const float* __restrict__ rdb,
            us* __restrict__ pbf, int n)
{
  int i = blockIdx.x * 256 + threadIdx.x;
  if (i >= n) return;
  float v = pbuf[i] + rdb[i & 63];
  pbuf[i] = v;
  if (pbf) pbf[i] = f2bf(v);
}

// softmax over groups of 8; groups i >= biasFrom get +bias2[(i&7)*8+j] first
__global__ __launch_bounds__(256)
void softmax8_kernel(const float* __restrict__ p, float* __restrict__ probs,
                     const float* __restrict__ bias2, int biasFrom, int total)
{
  int i = blockIdx.x * 256 + threadIdx.x;
  if (i >= total) return;
  const float4 lo = *(const float4*)(p + (size_t)i * 8);
  const float4 hi = *(const float4*)(p + (size_t)i * 8 + 4);
  float v[8] = { lo.x, lo.y, lo.z, lo.w, hi.x, hi.y, hi.z, hi.w };
  if (i >= biasFrom) {
    const float* bb = bias2 + (i & 7) * 8;
#pragma unroll
    for (int j = 0; j < 8; ++j) v[j] += bb[j];
  }
  float m = v[0];
#pragma unroll
  for (int j = 1; j < 8; ++j) m = fmaxf(m, v[j]);
  float s = 0.f;
#pragma unroll
  for (int j = 0; j < 8; ++j) { v[j] = __expf(v[j] - m); s += v[j]; }
  float inv = 1.f / s;
  float4 olo = { v[0]*inv, v[1]*inv, v[2]*inv, v[3]*inv };
  float4 ohi = { v[4]*inv, v[5]*inv, v[6]*inv, v[7]*inv };
  *(float4*)(probs + (size_t)i * 8)     = olo;
  *(float4*)(probs + (size_t)i * 8 + 4) = ohi;
}

// out[i*sOutE + bl*sOutB + d] = sum_j P[bg,i,j]*he[j,bl,d]; block per local b
__global__ __launch_bounds__(256)
void mix_kernel(const us* __restrict__ he, const float* __restrict__ probs_l,
                us* __restrict__ xx, int b0, int chunkB,
                long long sOutE, long long sOutB)
{
  const int bl = blockIdx.x;
  const int bg = b0 + bl;
  __shared__ float P[64];
  if (threadIdx.x < 64) P[threadIdx.x] = probs_l[(size_t)bg * 64 + threadIdx.x];
  __syncthreads();
  const int t = threadIdx.x;
  const size_t es = (size_t)chunkB * 1024;
  const size_t rbase = (size_t)bl * 1024 + (size_t)t * 4;
  const size_t wbase = (size_t)bl * sOutB + (size_t)t * 4;
  float hv[8][4];
#pragma unroll
  for (int j = 0; j < 8; ++j) {
    ushort4 h4 = *(const ushort4*)(he + (size_t)j * es + rbase);
    hv[j][0] = bf2f(h4.x); hv[j][1] = bf2f(h4.y);
    hv[j][2] = bf2f(h4.z); hv[j][3] = bf2f(h4.w);
  }
#pragma unroll
  for (int i = 0; i < 8; ++i) {
    float o0 = 0.f, o1 = 0.f, o2 = 0.f, o3 = 0.f;
#pragma unroll
    for (int j = 0; j < 8; ++j) {
      float pij = P[i * 8 + j];
      o0 += pij * hv[j][0]; o1 += pij * hv[j][1];
      o2 += pij * hv[j][2]; o3 += pij * hv[j][3];
    }
    ushort4 ov = { f2bf(o0), f2bf(o1), f2bf(o2), f2bf(o3) };
    *(ushort4*)(xx + (size_t)i * sOutE + wbase) = ov;
  }
}

// ---------------------------------------------------------------------------
extern "C" void kernel_launch(void* const* d_in, const int* in_sizes, int n_in,
                              void* d_out, int out_size, void* d_ws, size_t ws_size,
                              hipStream_t stream)
{
  const float* x   = (const float*)d_in[0];
  const float* sW1 = (const float*)d_in[1];
  const float* sb1 = (const float*)d_in[2];
  const float* sW2 = (const float*)d_in[3];
  const float* sb2 = (const float*)d_in[4];
  const float* sW3 = (const float*)d_in[5];
  const float* sb3 = (const float*)d_in[6];
  const float* tW  = (const float*)d_in[7];
  const float* tb  = (const float*)d_in[8];
  const float* rdW = (const float*)d_in[9];
  const float* rdb = (const float*)d_in[10];
  const float* ruW = (const float*)d_in[11];
  const float* rub = (const float*)d_in[12];
  const float* eW  = (const float*)d_in[13];
  const float* eb  = (const float*)d_in[14];
  const float* aW  = (const float*)d_in[15];
  const float* ab  = (const float*)d_in[16];
  const float* cW  = (const float*)d_in[17];
  const float* cb  = (const float*)d_in[18];
  float* out = (float*)d_out;

  const int B = 8192;
  const size_t BD = (size_t)B * 1024;
  char* ws = (char*)d_ws;

  // ---- arena: persistent region -------------------------------------------
  size_t o = 0;
  auto take = [&](size_t bytes) { size_t r = o; o = (o + bytes + 255) & ~(size_t)255; return r; };
  const size_t off_s1t  = take((size_t)512 * 128 * 2);
  const size_t off_s2t  = take((size_t)512 * 512 * 2);
  const size_t off_s3t  = take((size_t)1024 * 512 * 2);
  const size_t off_tWt  = take((size_t)1024 * 64 * 2);
  const size_t off_rdt  = take((size_t)2 * 64 * 1024 * 2);
  const size_t off_rut  = take((size_t)1024 * 64 * 2);
  const size_t off_eWt  = take((size_t)16 * 1024 * 1024 * 2);
  const size_t off_fobs = take(BD * 2);
  const size_t off_probs= take((size_t)2 * B * 64 * 4);
  const size_t off_Wh   = take((size_t)9 * 8192 * 2);
  const size_t P0 = o;
  // ---- scratch overlays (routing phase) -----------------------------------
  const size_t off_rin  = P0;                 // also h1
  const size_t off_rbuf = off_rin + BD * 2;   // also h2, u
  const size_t off_pbuf = off_rbuf + BD * 2;
  const size_t off_pbf  = off_pbuf + (size_t)2 * B * 64 * 4;
  const size_t off_obs  = off_pbf + (size_t)B * 64 * 2;
  const size_t off_task = off_obs + (size_t)B * 128 * 2;
  const size_t routing_end = off_task + (size_t)B * 64 * 2;

  // ---- expert-stage chunk selection (he/xx overlay scratch at P0) ---------
  int chunk = 0;
  const int cands[4] = {8192, 4096, 2048, 1024};
  for (int i = 0; i < 4; ++i) {
    size_t need = P0 + (size_t)cands[i] * 32768;  // he + xx
    if (need <= ws_size) { chunk = cands[i]; break; }
  }
  if (!chunk || routing_end > ws_size) return;

  us* s1t  = (us*)(ws + off_s1t);
  us* s2t  = (us*)(ws + off_s2t);
  us* s3t  = (us*)(ws + off_s3t);
  us* tWt  = (us*)(ws + off_tWt);
  us* rdt  = (us*)(ws + off_rdt);
  us* rut  = (us*)(ws + off_rut);
  us* eWt  = (us*)(ws + off_eWt);
  us* fobs = (us*)(ws + off_fobs);
  float* probs = (float*)(ws + off_probs);
  us* Wh   = (us*)(ws + off_Wh);
  us* rin  = (us*)(ws + off_rin);
  us* rbuf = (us*)(ws + off_rbuf);
  float* pbuf = (float*)(ws + off_pbuf);
  us* pbf  = (us*)(ws + off_pbf);
  us* obs_bf  = (us*)(ws + off_obs);
  us* task_bf = (us*)(ws + off_task);
  us* h1 = rin;
  us* h2 = rbuf;
  us* he = (us*)(ws + P0);
  us* xx = (us*)(ws + P0 + (size_t)chunk * 16384);  // also b-major for head

  // ---- fused prep: transposes + Wh + pbuf zero + out bias + x split -------
  prep_kernel<<<dim3(28288), 256, 0, stream>>>(x, sW1, sW2, sW3, tW, rdW, ruW,
      eW, aW, cW, ab, cb, obs_bf, task_bf, s1t, s2t, s3t, tWt, rdt, rut,
      eWt, Wh, pbuf, out);

  // ---- shared MLP ---------------------------------------------------------
  gemm_main<true, true, false, false, false><<<dim3(4, 64, 1), 256, 0, stream>>>(
      obs_bf, s1t, sb1, h1, (us*)0, (const us*)0, 512, 128, 128, 128, 0, 0, 0, 0);
  gemm_main<true, true, false, false, false><<<dim3(4, 64, 1), 256, 0, stream>>>(
      h1, s2t, sb2, h2, (us*)0, (const us*)0, 512, 512, 512, 512, 0, 0, 0, 0);
  gemm_main<true, false, false, false, false><<<dim3(8, 64, 1), 256, 0, stream>>>(
      h2, s3t, sb3, fobs, (us*)0, (const us*)0, 1024, 512, 512, 512, 0, 0, 0, 0);
  // z-GEMM fused: rin = relu(task@tW+tb)*fobs ; rbuf = relu(rin)
  gemm_main<true, true, true, false, true><<<dim3(8, 64, 1), 256, 0, stream>>>(
      task_bf, tWt, tb, rin, rbuf, fobs, 1024, 64, 64, 64, 0, 0, 0, 0);

  // ---- routing (layers 0,1; layer 2 is dead code) -------------------------
  gemm_splitk<<<dim3(1, 64, 4), 256, 0, stream>>>(rbuf, rdt, pbuf,
      64, 256, 1024, 1024, 256, 256, 0, 0, 0);                       // p0
  mk_pbf<<<dim3((B * 64 + 255) / 256), 256, 0, stream>>>(pbuf, rdb, pbf, B * 64);
  // u-GEMM fused: rbuf = relu((pbf@ruW+rub) * rin)
  gemm_main<true, false, true, true, false><<<dim3(8, 64, 1), 256, 0, stream>>>(
      pbf, rut, rub, rbuf, (us*)0, rin, 1024, 64, 64, 64, 0, 0, 0, 0);
  gemm_splitk<<<dim3(1, 64, 4), 256, 0, stream>>>(rbuf, rdt + 65536,
      pbuf + (size_t)B * 64, 64, 256, 1024, 1024, 256, 256, 0, 0, 0); // p1
  softmax8_kernel<<<dim3((2 * B * 8 + 255) / 256), 256, 0, stream>>>(
      pbuf, probs, rdb + 64, B * 8, 2 * B * 8);

  // ---- expert stage, chunked over batch -----------------------------------
  const long long sHE = (long long)chunk * 1024;
  for (int b0 = 0; b0 < B; b0 += chunk) {
    gemm_main<true, true, false, false, false><<<dim3(8, chunk / 128, 8), 256, 0, stream>>>(
        fobs + (size_t)b0 * 1024, eWt, eb, he, (us*)0, (const us*)0,
        1024, 1024, 1024, 1024, 0, 1048576, 1024, sHE);
    mix_kernel<<<dim3(chunk), 256, 0, stream>>>(he, probs, xx, b0, chunk, sHE, 1024);
    gemm_main<true, true, false, false, false><<<dim3(8, chunk / 128, 8), 256, 0, stream>>>(
        xx, eWt + (size_t)8 * 1048576, eb + 8192, he, (us*)0, (const us*)0,
        1024, 1024, 1024, 1024, sHE, 1048576, 1024, sHE);
    // xx reused in b-major layout [bl][e*1024+d] for the head GEMM
    mix_kernel<<<dim3(chunk), 256, 0, stream>>>(he, probs + (size_t)B * 64, xx,
        b0, chunk, 1024, 8192);
    // heads: M=chunk, N=9, K=8192, split-K=4, atomic direct into out
    gemm_splitk<<<dim3(1, chunk / 128, 4), 256, 0, stream>>>(
        xx, Wh, out, 9, 2048, 8192, 8192, 2048, 2048, 1, b0, B);
  }
}